// Round 3
// baseline (892.590 us; speedup 1.0000x reference)
//
#include <hip/hip_runtime.h>
#include <hip/hip_bf16.h>

#define NNODES 50000
#define NEDGES 800000
#define FIN    128
#define HID    64
#define HEADS  4
#define NGRAPH 256
#define NCLS   10
#define DTOT   256   // HEADS*HID
#define ALPHA  0.01f

// ---------------- CSR build ----------------
__global__ void k_deg(const int* __restrict__ dst, int* __restrict__ deg, int E) {
    int e = blockIdx.x * blockDim.x + threadIdx.x;
    if (e < E) atomicAdd(&deg[dst[e]], 1);
}

__global__ __launch_bounds__(1024) void k_scan(const int* __restrict__ deg,
                                               int* __restrict__ rowptr,
                                               int n, int total) {
    __shared__ int sums[1024];
    int t = threadIdx.x;
    int chunk = (n + 1023) >> 10;
    int beg = t * chunk;
    int end = beg + chunk; if (end > n) end = n;
    int s = 0;
    for (int i = beg; i < end; ++i) s += deg[i];
    sums[t] = s;
    __syncthreads();
    for (int off = 1; off < 1024; off <<= 1) {
        int v = (t >= off) ? sums[t - off] : 0;
        __syncthreads();
        sums[t] += v;
        __syncthreads();
    }
    int run = sums[t] - s;   // exclusive prefix of this chunk
    for (int i = beg; i < end; ++i) { rowptr[i] = run; run += deg[i]; }
    if (t == 1023) rowptr[n] = total;
}

__global__ void k_fill(const int* __restrict__ src, const int* __restrict__ dst,
                       const int* __restrict__ rowptr, int* __restrict__ cursor,
                       int* __restrict__ esrc, int E) {
    int e = blockIdx.x * blockDim.x + threadIdx.x;
    if (e >= E) return;
    int d = dst[e];
    int pos = rowptr[d] + atomicAdd(&cursor[d], 1);
    esrc[pos] = src[e];
}

// ---------------- graph segment starts (batch is sorted) ----------------
__global__ void k_gstart(const int* __restrict__ batch, int* __restrict__ gstart, int n) {
    int i = blockIdx.x * blockDim.x + threadIdx.x;
    if (i >= n) return;
    int b = batch[i];
    if (i == 0) {
        for (int g = 0; g <= b; ++g) gstart[g] = 0;
    } else {
        int pb = batch[i - 1];
        if (pb != b) for (int g = pb + 1; g <= b; ++g) gstart[g] = i;
    }
    if (i == n - 1) {
        for (int g = b + 1; g <= NGRAPH; ++g) gstart[g] = n;
    }
}

// ---------------- GEMM: C[M,256] = A[M,K] @ B[K,256], fp32 ----------------
__global__ __launch_bounds__(256) void k_gemm(const float* __restrict__ A,
                                              const float* __restrict__ B,
                                              float* __restrict__ C, int M, int K) {
    __shared__ float As[16][68];
    __shared__ float Bs[16][68];
    const int t  = threadIdx.x;
    const int m0 = blockIdx.y * 64;
    const int n0 = blockIdx.x * 64;
    const int ar = t >> 2;            // 0..63 row in tile
    const int ak = (t & 3) * 4;       // 0,4,8,12
    const int bn = t & 63;
    const int bk = (t >> 6) * 4;
    const int tx = t & 15, ty = t >> 4;
    const bool arow_ok = (m0 + ar) < M;
    float acc[4][4] = {};
    for (int k0 = 0; k0 < K; k0 += 16) {
        float4 av = make_float4(0.f, 0.f, 0.f, 0.f);
        if (arow_ok) av = *(const float4*)&A[(size_t)(m0 + ar) * K + k0 + ak];
        As[ak + 0][ar] = av.x;
        As[ak + 1][ar] = av.y;
        As[ak + 2][ar] = av.z;
        As[ak + 3][ar] = av.w;
#pragma unroll
        for (int i = 0; i < 4; ++i)
            Bs[bk + i][bn] = B[(size_t)(k0 + bk + i) * DTOT + n0 + bn];
        __syncthreads();
#pragma unroll
        for (int kk = 0; kk < 16; ++kk) {
            float a4[4], b4[4];
#pragma unroll
            for (int i = 0; i < 4; ++i) a4[i] = As[kk][ty * 4 + i];
#pragma unroll
            for (int j = 0; j < 4; ++j) b4[j] = Bs[kk][tx * 4 + j];
#pragma unroll
            for (int i = 0; i < 4; ++i)
#pragma unroll
                for (int j = 0; j < 4; ++j) acc[i][j] += a4[i] * b4[j];
        }
        __syncthreads();
    }
#pragma unroll
    for (int i = 0; i < 4; ++i) {
        int row = m0 + ty * 4 + i;
        if (row < M) {
            float4 v = make_float4(acc[i][0], acc[i][1], acc[i][2], acc[i][3]);
            *(float4*)&C[(size_t)row * DTOT + n0 + tx * 4] = v;
        }
    }
}

// ---------------- attention logits: ls/ld[n,h] = <Wh[n,h,:], a_*[h,:]> ----------------
__global__ __launch_bounds__(256) void k_logits(const float* __restrict__ Wh,
                                                const float* __restrict__ a_src,
                                                const float* __restrict__ a_dst,
                                                float* __restrict__ ls, float* __restrict__ ld_) {
    int n = blockIdx.x, t = threadIdx.x;
    int h = t >> 6;
    float w  = Wh[(size_t)n * DTOT + t];
    float vs = w * a_src[t];
    float vd = w * a_dst[t];
#pragma unroll
    for (int off = 32; off; off >>= 1) {
        vs += __shfl_down(vs, off);
        vd += __shfl_down(vd, off);
    }
    if ((t & 63) == 0) {
        ls[n * HEADS + h]  = vs;
        ld_[n * HEADS + h] = vd;
    }
}

// ---------------- per-node online-softmax aggregation + ELU ----------------
__global__ __launch_bounds__(256) void k_aggregate(const int* __restrict__ rowptr,
                                                   const int* __restrict__ esrc,
                                                   const float* __restrict__ Wh,
                                                   const float* __restrict__ ls,
                                                   const float* __restrict__ ld_,
                                                   float* __restrict__ out) {
    int i = blockIdx.x;
    int t = threadIdx.x;
    int h = t >> 6;
    float ldv = ld_[i * HEADS + h];
    int e0 = rowptr[i], e1 = rowptr[i + 1];
    float m = -INFINITY, z = 0.f, acc = 0.f;
    for (int e = e0; e < e1; ++e) {
        int s = esrc[e];
        float lv = ls[s * HEADS + h] + ldv;
        float ev = lv > 0.f ? lv : ALPHA * lv;
        float nm = fmaxf(m, ev);
        float sc = __expf(m - nm);
        float p  = __expf(ev - nm);
        float w  = Wh[(size_t)s * DTOT + t];
        acc = acc * sc + p * w;
        z   = z * sc + p;
        m   = nm;
    }
    float v = acc / (z + 1e-16f);
    float o = v > 0.f ? v : (__expf(v) - 1.f);
    out[(size_t)i * DTOT + t] = o;
}

// ---------------- pooling (max + mean per graph) ----------------
__global__ __launch_bounds__(256) void k_pool(const float* __restrict__ h2,
                                              const int* __restrict__ gstart,
                                              float* __restrict__ pooled) {
    int g = blockIdx.x, f = threadIdx.x;
    int s = gstart[g], e = gstart[g + 1];
    float mx = -INFINITY, sm = 0.f;
    for (int n = s; n < e; ++n) {
        float v = h2[(size_t)n * DTOT + f];
        mx = fmaxf(mx, v);
        sm += v;
    }
    int cnt = e - s;
    if (cnt <= 0) mx = 0.f;
    pooled[g * 2 * DTOT + f]        = mx;
    pooled[g * 2 * DTOT + DTOT + f] = sm / (float)(cnt > 0 ? cnt : 1);
}

// ---------------- final linear (fp32 output!) ----------------
__global__ __launch_bounds__(64) void k_final(const float* __restrict__ pooled,
                                              const float* __restrict__ W,
                                              const float* __restrict__ b,
                                              float* __restrict__ out) {
    int g = blockIdx.x, lane = threadIdx.x;
    for (int c = 0; c < NCLS; ++c) {
        float acc = 0.f;
        for (int k = lane; k < 2 * DTOT; k += 64)
            acc += pooled[g * 2 * DTOT + k] * W[k * NCLS + c];
#pragma unroll
        for (int off = 32; off; off >>= 1) acc += __shfl_down(acc, off);
        if (lane == 0)
            out[g * NCLS + c] = acc + b[c];
    }
}

extern "C" void kernel_launch(void* const* d_in, const int* in_sizes, int n_in,
                              void* d_out, int out_size, void* d_ws, size_t ws_size,
                              hipStream_t stream) {
    const float* x     = (const float*)d_in[0];
    const int*   ei    = (const int*)d_in[1];
    const int*   batch = (const int*)d_in[2];
    const float* W1    = (const float*)d_in[3];
    const float* a1s   = (const float*)d_in[4];
    const float* a1d   = (const float*)d_in[5];
    const float* W2    = (const float*)d_in[6];
    const float* a2s   = (const float*)d_in[7];
    const float* a2d   = (const float*)d_in[8];
    const float* linW  = (const float*)d_in[9];
    const float* linb  = (const float*)d_in[10];
    float* out = (float*)d_out;   // reference output dtype is float32

    const int* src = ei;
    const int* dst = ei + NEDGES;

    size_t off = 0;
    char* base = (char*)d_ws;
    auto alloc = [&](size_t bytes) -> void* {
        void* p = base + off;
        off += (bytes + 255) & ~(size_t)255;
        return p;
    };
    float* bufA   = (float*)alloc((size_t)NNODES * DTOT * 4);   // Wh (layer1), then Wh2
    float* bufB   = (float*)alloc((size_t)NNODES * DTOT * 4);   // h1, then h2
    float* ls     = (float*)alloc((size_t)NNODES * HEADS * 4);
    float* ld_    = (float*)alloc((size_t)NNODES * HEADS * 4);
    int*   deg    = (int*)alloc((size_t)NNODES * 4);
    int*   rowptr = (int*)alloc((size_t)(NNODES + 1) * 4);
    int*   cursor = (int*)alloc((size_t)NNODES * 4);
    int*   esrc   = (int*)alloc((size_t)NEDGES * 4);
    int*   gstart = (int*)alloc((size_t)(NGRAPH + 1) * 4);
    float* pooled = (float*)alloc((size_t)NGRAPH * 2 * DTOT * 4);

    hipMemsetAsync(deg, 0, (size_t)NNODES * 4, stream);
    hipMemsetAsync(cursor, 0, (size_t)NNODES * 4, stream);

    int eb = (NEDGES + 255) / 256;
    int nb = (NNODES + 255) / 256;

    k_deg<<<eb, 256, 0, stream>>>(dst, deg, NEDGES);
    k_scan<<<1, 1024, 0, stream>>>(deg, rowptr, NNODES, NEDGES);
    k_fill<<<eb, 256, 0, stream>>>(src, dst, rowptr, cursor, esrc, NEDGES);
    k_gstart<<<nb, 256, 0, stream>>>(batch, gstart, NNODES);

    dim3 ggrid(DTOT / 64, (NNODES + 63) / 64);

    // Layer 1
    k_gemm<<<ggrid, 256, 0, stream>>>(x, W1, bufA, NNODES, FIN);
    k_logits<<<NNODES, 256, 0, stream>>>(bufA, a1s, a1d, ls, ld_);
    k_aggregate<<<NNODES, 256, 0, stream>>>(rowptr, esrc, bufA, ls, ld_, bufB);

    // Layer 2
    k_gemm<<<ggrid, 256, 0, stream>>>(bufB, W2, bufA, NNODES, DTOT);
    k_logits<<<NNODES, 256, 0, stream>>>(bufA, a2s, a2d, ls, ld_);
    k_aggregate<<<NNODES, 256, 0, stream>>>(rowptr, esrc, bufA, ls, ld_, bufB);

    // Pool + head
    k_pool<<<NGRAPH, 256, 0, stream>>>(bufB, gstart, pooled);
    k_final<<<NGRAPH, 64, 0, stream>>>(pooled, linW, linb, out);
}

// Round 4
// 685.069 us; speedup vs baseline: 1.3029x; 1.3029x over previous
//
#include <hip/hip_runtime.h>
#include <hip/hip_bf16.h>

#define NNODES 50000
#define NEDGES 800000
#define FIN    128
#define HID    64
#define HEADS  4
#define NGRAPH 256
#define NCLS   10
#define DTOT   256   // HEADS*HID
#define ALPHA  0.01f

// ---------------- CSR build ----------------
__global__ void k_deg(const int* __restrict__ dst, int* __restrict__ deg, int E) {
    int e = blockIdx.x * blockDim.x + threadIdx.x;
    if (e < E) atomicAdd(&deg[dst[e]], 1);
}

__global__ __launch_bounds__(1024) void k_scan(const int* __restrict__ deg,
                                               int* __restrict__ rowptr,
                                               int n, int total) {
    __shared__ int sums[1024];
    int t = threadIdx.x;
    int chunk = (n + 1023) >> 10;
    int beg = t * chunk;
    int end = beg + chunk; if (end > n) end = n;
    int s = 0;
    for (int i = beg; i < end; ++i) s += deg[i];
    sums[t] = s;
    __syncthreads();
    for (int off = 1; off < 1024; off <<= 1) {
        int v = (t >= off) ? sums[t - off] : 0;
        __syncthreads();
        sums[t] += v;
        __syncthreads();
    }
    int run = sums[t] - s;   // exclusive prefix of this chunk
    for (int i = beg; i < end; ++i) { rowptr[i] = run; run += deg[i]; }
    if (t == 1023) rowptr[n] = total;
}

__global__ void k_fill(const int* __restrict__ src, const int* __restrict__ dst,
                       const int* __restrict__ rowptr, int* __restrict__ cursor,
                       int* __restrict__ esrc, int E) {
    int e = blockIdx.x * blockDim.x + threadIdx.x;
    if (e >= E) return;
    int d = dst[e];
    int pos = rowptr[d] + atomicAdd(&cursor[d], 1);
    esrc[pos] = src[e];
}

// ---------------- graph segment starts (batch is sorted) ----------------
__global__ void k_gstart(const int* __restrict__ batch, int* __restrict__ gstart, int n) {
    int i = blockIdx.x * blockDim.x + threadIdx.x;
    if (i >= n) return;
    int b = batch[i];
    if (i == 0) {
        for (int g = 0; g <= b; ++g) gstart[g] = 0;
    } else {
        int pb = batch[i - 1];
        if (pb != b) for (int g = pb + 1; g <= b; ++g) gstart[g] = i;
    }
    if (i == n - 1) {
        for (int g = b + 1; g <= NGRAPH; ++g) gstart[g] = n;
    }
}

// ---------------- GEMM: Whbf[M,256](bf16) = A[M,K] @ B[K,256]; fused logits ----------------
// Tile 64x64 (one head per x-tile). Epilogue also computes
// ls[row,h] = <Wh[row,h,:], a_src[h,:]> and ld likewise, from fp32 accumulators.
__global__ __launch_bounds__(256) void k_gemm(const float* __restrict__ A,
                                              const float* __restrict__ B,
                                              ushort* __restrict__ Cbf,
                                              float* __restrict__ ls,
                                              float* __restrict__ ld_,
                                              const float* __restrict__ a_src,
                                              const float* __restrict__ a_dst,
                                              int M, int K) {
    __shared__ float As[16][68];
    __shared__ float Bs[16][68];
    const int t  = threadIdx.x;
    const int m0 = blockIdx.y * 64;
    const int n0 = blockIdx.x * 64;
    const int h  = blockIdx.x;        // head index (tile == head)
    const int ar = t >> 2;            // 0..63 row in tile
    const int ak = (t & 3) * 4;       // 0,4,8,12
    const int bn = t & 63;
    const int bk = (t >> 6) * 4;
    const int tx = t & 15, ty = t >> 4;
    const bool arow_ok = (m0 + ar) < M;
    float acc[4][4] = {};
    for (int k0 = 0; k0 < K; k0 += 16) {
        float4 av = make_float4(0.f, 0.f, 0.f, 0.f);
        if (arow_ok) av = *(const float4*)&A[(size_t)(m0 + ar) * K + k0 + ak];
        As[ak + 0][ar] = av.x;
        As[ak + 1][ar] = av.y;
        As[ak + 2][ar] = av.z;
        As[ak + 3][ar] = av.w;
#pragma unroll
        for (int i = 0; i < 4; ++i)
            Bs[bk + i][bn] = B[(size_t)(k0 + bk + i) * DTOT + n0 + bn];
        __syncthreads();
#pragma unroll
        for (int kk = 0; kk < 16; ++kk) {
            float a4[4], b4[4];
#pragma unroll
            for (int i = 0; i < 4; ++i) a4[i] = As[kk][ty * 4 + i];
#pragma unroll
            for (int j = 0; j < 4; ++j) b4[j] = Bs[kk][tx * 4 + j];
#pragma unroll
            for (int i = 0; i < 4; ++i)
#pragma unroll
                for (int j = 0; j < 4; ++j) acc[i][j] += a4[i] * b4[j];
        }
        __syncthreads();
    }
    // store bf16 output (4 values -> 8B)
#pragma unroll
    for (int i = 0; i < 4; ++i) {
        int row = m0 + ty * 4 + i;
        if (row < M) {
            union { ushort u[4]; uint2 v; } pk;
#pragma unroll
            for (int j = 0; j < 4; ++j)
                pk.u[j] = __bfloat16_as_ushort(__float2bfloat16(acc[i][j]));
            *(uint2*)&Cbf[(size_t)row * DTOT + n0 + tx * 4] = pk.v;
        }
    }
    // fused attention-logit reduction (fp32-exact, pre-bf16)
    float as4[4], ad4[4];
#pragma unroll
    for (int j = 0; j < 4; ++j) {
        as4[j] = a_src[h * HID + tx * 4 + j];
        ad4[j] = a_dst[h * HID + tx * 4 + j];
    }
    __syncthreads();
    float* sls = &As[0][0];           // [16][68] layout: sls[tx*68 + row_local]
    float* sld = &Bs[0][0];
#pragma unroll
    for (int i = 0; i < 4; ++i) {
        float ps = 0.f, pd = 0.f;
#pragma unroll
        for (int j = 0; j < 4; ++j) {
            ps += acc[i][j] * as4[j];
            pd += acc[i][j] * ad4[j];
        }
        sls[tx * 68 + ty * 4 + i] = ps;
        sld[tx * 68 + ty * 4 + i] = pd;
    }
    __syncthreads();
    if (t < 64) {
        int row = m0 + t;
        if (row < M) {
            float s1 = 0.f, s2 = 0.f;
#pragma unroll
            for (int k = 0; k < 16; ++k) {
                s1 += sls[k * 68 + t];
                s2 += sld[k * 68 + t];
            }
            ls[row * HEADS + h]  = s1;
            ld_[row * HEADS + h] = s2;
        }
    }
}

// ---------------- attention softmax per node: attn[e,h] = exp(lrelu(ls[s]+ld[i]) - m)/z ----------------
// One wave per node; lanes = 16 edges x 4 heads.
__global__ __launch_bounds__(256) void k_attn(const int* __restrict__ rowptr,
                                              const int* __restrict__ esrc,
                                              const float* __restrict__ ls,
                                              const float* __restrict__ ld_,
                                              float* __restrict__ attn) {
    int wave = threadIdx.x >> 6;
    int lane = threadIdx.x & 63;
    int i = blockIdx.x * 4 + wave;
    if (i >= NNODES) return;
    int h  = lane & 3;
    int eo = lane >> 2;
    int e0 = rowptr[i], e1 = rowptr[i + 1];
    float ldv = ld_[i * HEADS + h];
    float m = -INFINITY, z = 0.f;
    for (int base = e0; base < e1; base += 16) {
        int e = base + eo;
        float ev = -INFINITY;
        if (e < e1) {
            float lv = ls[esrc[e] * HEADS + h] + ldv;
            ev = lv > 0.f ? lv : ALPHA * lv;
        }
        float cm = ev;
        cm = fmaxf(cm, __shfl_xor(cm, 4));
        cm = fmaxf(cm, __shfl_xor(cm, 8));
        cm = fmaxf(cm, __shfl_xor(cm, 16));
        cm = fmaxf(cm, __shfl_xor(cm, 32));
        float nm = fmaxf(m, cm);
        float p = (e < e1) ? __expf(ev - nm) : 0.f;
        float cz = p;
        cz += __shfl_xor(cz, 4);
        cz += __shfl_xor(cz, 8);
        cz += __shfl_xor(cz, 16);
        cz += __shfl_xor(cz, 32);
        z = z * __expf(m - nm) + cz;
        m = nm;
    }
    float inv = 1.f / (z + 1e-16f);
    for (int base = e0; base < e1; base += 16) {
        int e = base + eo;
        if (e < e1) {
            float lv = ls[esrc[e] * HEADS + h] + ldv;
            float ev = lv > 0.f ? lv : ALPHA * lv;
            attn[(size_t)e * HEADS + h] = __expf(ev - m) * inv;
        }
    }
}

// ---------------- gather-aggregate + ELU: out[i,:] = elu(sum_e attn[e]*Whbf[src_e,:]) ----------------
// 2 nodes per block; 128 threads/node; 2 bf16 channels per thread (4B loads).
__global__ __launch_bounds__(256) void k_gather(const int* __restrict__ rowptr,
                                                const int* __restrict__ esrc,
                                                const ushort* __restrict__ Whbf,
                                                const float* __restrict__ attn,
                                                float* __restrict__ out) {
    int tid  = threadIdx.x;
    int half = tid >> 7;
    int t    = tid & 127;
    int i    = blockIdx.x * 2 + half;
    int head = t >> 5;
    int e0 = rowptr[i], e1 = rowptr[i + 1];
    float acc0 = 0.f, acc1 = 0.f;
    int e = e0;
    for (; e + 1 < e1; e += 2) {
        int s0 = esrc[e], s1 = esrc[e + 1];
        float a0 = attn[(size_t)e * HEADS + head];
        float a1 = attn[(size_t)(e + 1) * HEADS + head];
        unsigned u0 = *(const unsigned*)&Whbf[(size_t)s0 * DTOT + 2 * t];
        unsigned u1 = *(const unsigned*)&Whbf[(size_t)s1 * DTOT + 2 * t];
        acc0 = fmaf(a0, __uint_as_float(u0 << 16), acc0);
        acc1 = fmaf(a0, __uint_as_float(u0 & 0xffff0000u), acc1);
        acc0 = fmaf(a1, __uint_as_float(u1 << 16), acc0);
        acc1 = fmaf(a1, __uint_as_float(u1 & 0xffff0000u), acc1);
    }
    if (e < e1) {
        int s0 = esrc[e];
        float a0 = attn[(size_t)e * HEADS + head];
        unsigned u0 = *(const unsigned*)&Whbf[(size_t)s0 * DTOT + 2 * t];
        acc0 = fmaf(a0, __uint_as_float(u0 << 16), acc0);
        acc1 = fmaf(a0, __uint_as_float(u0 & 0xffff0000u), acc1);
    }
    float v0 = acc0 > 0.f ? acc0 : __expf(acc0) - 1.f;
    float v1 = acc1 > 0.f ? acc1 : __expf(acc1) - 1.f;
    *(float2*)&out[(size_t)i * DTOT + 2 * t] = make_float2(v0, v1);
}

// ---------------- pooling (max + mean per graph) ----------------
__global__ __launch_bounds__(256) void k_pool(const float* __restrict__ h2,
                                              const int* __restrict__ gstart,
                                              float* __restrict__ pooled) {
    int g = blockIdx.x, f = threadIdx.x;
    int s = gstart[g], e = gstart[g + 1];
    float mx = -INFINITY, sm = 0.f;
    for (int n = s; n < e; ++n) {
        float v = h2[(size_t)n * DTOT + f];
        mx = fmaxf(mx, v);
        sm += v;
    }
    int cnt = e - s;
    if (cnt <= 0) mx = 0.f;
    pooled[g * 2 * DTOT + f]        = mx;
    pooled[g * 2 * DTOT + DTOT + f] = sm / (float)(cnt > 0 ? cnt : 1);
}

// ---------------- final linear (fp32 output) ----------------
__global__ __launch_bounds__(64) void k_final(const float* __restrict__ pooled,
                                              const float* __restrict__ W,
                                              const float* __restrict__ b,
                                              float* __restrict__ out) {
    int g = blockIdx.x, lane = threadIdx.x;
    for (int c = 0; c < NCLS; ++c) {
        float acc = 0.f;
        for (int k = lane; k < 2 * DTOT; k += 64)
            acc += pooled[g * 2 * DTOT + k] * W[k * NCLS + c];
#pragma unroll
        for (int off = 32; off; off >>= 1) acc += __shfl_down(acc, off);
        if (lane == 0)
            out[g * NCLS + c] = acc + b[c];
    }
}

extern "C" void kernel_launch(void* const* d_in, const int* in_sizes, int n_in,
                              void* d_out, int out_size, void* d_ws, size_t ws_size,
                              hipStream_t stream) {
    const float* x     = (const float*)d_in[0];
    const int*   ei    = (const int*)d_in[1];
    const int*   batch = (const int*)d_in[2];
    const float* W1    = (const float*)d_in[3];
    const float* a1s   = (const float*)d_in[4];
    const float* a1d   = (const float*)d_in[5];
    const float* W2    = (const float*)d_in[6];
    const float* a2s   = (const float*)d_in[7];
    const float* a2d   = (const float*)d_in[8];
    const float* linW  = (const float*)d_in[9];
    const float* linb  = (const float*)d_in[10];
    float* out = (float*)d_out;

    const int* src = ei;
    const int* dst = ei + NEDGES;

    size_t off = 0;
    char* base = (char*)d_ws;
    auto alloc = [&](size_t bytes) -> void* {
        void* p = base + off;
        off += (bytes + 255) & ~(size_t)255;
        return p;
    };
    ushort* Whbf  = (ushort*)alloc((size_t)NNODES * DTOT * 2);     // bf16 Wh (per layer)
    float*  bufH  = (float*)alloc((size_t)NNODES * DTOT * 4);      // h1, then h2
    float*  attn  = (float*)alloc((size_t)NEDGES * HEADS * 4);     // normalized attention
    float*  ls    = (float*)alloc((size_t)NNODES * HEADS * 4);
    float*  ld_   = (float*)alloc((size_t)NNODES * HEADS * 4);
    int*    deg    = (int*)alloc((size_t)NNODES * 4);
    int*    rowptr = (int*)alloc((size_t)(NNODES + 1) * 4);
    int*    cursor = (int*)alloc((size_t)NNODES * 4);
    int*    esrc   = (int*)alloc((size_t)NEDGES * 4);
    int*    gstart = (int*)alloc((size_t)(NGRAPH + 1) * 4);
    float*  pooled = (float*)alloc((size_t)NGRAPH * 2 * DTOT * 4);

    hipMemsetAsync(deg, 0, (size_t)NNODES * 4, stream);
    hipMemsetAsync(cursor, 0, (size_t)NNODES * 4, stream);

    int eb = (NEDGES + 255) / 256;
    int nb = (NNODES + 255) / 256;

    k_deg<<<eb, 256, 0, stream>>>(dst, deg, NEDGES);
    k_scan<<<1, 1024, 0, stream>>>(deg, rowptr, NNODES, NEDGES);
    k_fill<<<eb, 256, 0, stream>>>(src, dst, rowptr, cursor, esrc, NEDGES);
    k_gstart<<<nb, 256, 0, stream>>>(batch, gstart, NNODES);

    dim3 ggrid(DTOT / 64, (NNODES + 63) / 64);

    // Layer 1
    k_gemm<<<ggrid, 256, 0, stream>>>(x, W1, Whbf, ls, ld_, a1s, a1d, NNODES, FIN);
    k_attn<<<(NNODES + 3) / 4, 256, 0, stream>>>(rowptr, esrc, ls, ld_, attn);
    k_gather<<<NNODES / 2, 256, 0, stream>>>(rowptr, esrc, Whbf, attn, bufH);

    // Layer 2
    k_gemm<<<ggrid, 256, 0, stream>>>(bufH, W2, Whbf, ls, ld_, a2s, a2d, NNODES, DTOT);
    k_attn<<<(NNODES + 3) / 4, 256, 0, stream>>>(rowptr, esrc, ls, ld_, attn);
    k_gather<<<NNODES / 2, 256, 0, stream>>>(rowptr, esrc, Whbf, attn, bufH);

    // Pool + head
    k_pool<<<NGRAPH, 256, 0, stream>>>(bufH, gstart, pooled);
    k_final<<<NGRAPH, 64, 0, stream>>>(pooled, linW, linb, out);
}

// Round 5
// 596.619 us; speedup vs baseline: 1.4961x; 1.1483x over previous
//
#include <hip/hip_runtime.h>
#include <hip/hip_bf16.h>

#define NNODES 50000
#define NEDGES 800000
#define FIN    128
#define HID    64
#define HEADS  4
#define NGRAPH 256
#define NCLS   10
#define DTOT   256   // HEADS*HID
#define ALPHA  0.01f

typedef short bf16x8 __attribute__((ext_vector_type(8)));
typedef float f32x4  __attribute__((ext_vector_type(4)));

// ---------------- CSR build ----------------
__global__ void k_deg(const int* __restrict__ dst, int* __restrict__ deg, int E) {
    int e = blockIdx.x * blockDim.x + threadIdx.x;
    if (e < E) atomicAdd(&deg[dst[e]], 1);
}

__global__ __launch_bounds__(1024) void k_scan(const int* __restrict__ deg,
                                               int* __restrict__ rowptr,
                                               int n, int total) {
    __shared__ int sums[1024];
    int t = threadIdx.x;
    int chunk = (n + 1023) >> 10;
    int beg = t * chunk;
    int end = beg + chunk; if (end > n) end = n;
    int s = 0;
    for (int i = beg; i < end; ++i) s += deg[i];
    sums[t] = s;
    __syncthreads();
    for (int off = 1; off < 1024; off <<= 1) {
        int v = (t >= off) ? sums[t - off] : 0;
        __syncthreads();
        sums[t] += v;
        __syncthreads();
    }
    int run = sums[t] - s;   // exclusive prefix of this chunk
    for (int i = beg; i < end; ++i) { rowptr[i] = run; run += deg[i]; }
    if (t == 1023) rowptr[n] = total;
}

__global__ void k_fill(const int* __restrict__ src, const int* __restrict__ dst,
                       const int* __restrict__ rowptr, int* __restrict__ cursor,
                       int* __restrict__ esrc, int E) {
    int e = blockIdx.x * blockDim.x + threadIdx.x;
    if (e >= E) return;
    int d = dst[e];
    int pos = rowptr[d] + atomicAdd(&cursor[d], 1);
    esrc[pos] = src[e];
}

// ---------------- graph segment starts (batch is sorted) ----------------
__global__ void k_gstart(const int* __restrict__ batch, int* __restrict__ gstart, int n) {
    int i = blockIdx.x * blockDim.x + threadIdx.x;
    if (i >= n) return;
    int b = batch[i];
    if (i == 0) {
        for (int g = 0; g <= b; ++g) gstart[g] = 0;
    } else {
        int pb = batch[i - 1];
        if (pb != b) for (int g = pb + 1; g <= b; ++g) gstart[g] = i;
    }
    if (i == n - 1) {
        for (int g = b + 1; g <= NGRAPH; ++g) gstart[g] = n;
    }
}

// ---------------- fp32 -> bf16 bulk cast ----------------
__global__ __launch_bounds__(256) void k_cast(const float4* __restrict__ in,
                                              ushort4* __restrict__ out, int n4) {
    int i = blockIdx.x * blockDim.x + threadIdx.x;
    if (i >= n4) return;
    float4 v = in[i];
    ushort4 o;
    o.x = __bfloat16_as_ushort(__float2bfloat16(v.x));
    o.y = __bfloat16_as_ushort(__float2bfloat16(v.y));
    o.z = __bfloat16_as_ushort(__float2bfloat16(v.z));
    o.w = __bfloat16_as_ushort(__float2bfloat16(v.w));
    out[i] = o;
}

// ---------------- MFMA GEMM: Cbf[M,256](bf16) = Abf[M,K](bf16) @ B[K,256](fp32->bf16) ----------------
// Block: 4 waves, tile M=128 (wave = 32 rows) x N=64 (one head). B staged to LDS once,
// XOR-swizzled 16B chunks for conflict-free ds_read_b128. Fused fp32 logits epilogue.
template <int K>
__global__ __launch_bounds__(256) void k_gemm_mfma(const ushort* __restrict__ Abf,
                                                   const float* __restrict__ B,
                                                   ushort* __restrict__ Cbf,
                                                   float* __restrict__ ls,
                                                   float* __restrict__ ld_,
                                                   const float* __restrict__ a_src,
                                                   const float* __restrict__ a_dst,
                                                   int M) {
    __shared__ ushort Bl[64 * K];
    const int tid  = threadIdx.x;
    const int w    = tid >> 6;
    const int lane = tid & 63;
    const int l15  = lane & 15;
    const int quad = lane >> 4;
    const int m0    = blockIdx.y * 128;
    const int ntile = blockIdx.x;          // head index
    const int n0    = ntile * 64;

    // stage B tile (fp32 -> bf16), swizzled: element (n,k) at n*K + ((k/8 ^ (n&7))*8 + k%8)
    for (int idx = tid; idx < 64 * K; idx += 256) {
        int n = idx & 63, k = idx >> 6;
        float v = B[k * DTOT + n0 + n];
        int c = (k >> 3) ^ (n & 7);
        Bl[n * K + (c << 3) + (k & 7)] = __bfloat16_as_ushort(__float2bfloat16(v));
    }
    __syncthreads();

    f32x4 acc[2][4];
#pragma unroll
    for (int mf = 0; mf < 2; ++mf)
#pragma unroll
        for (int nf = 0; nf < 4; ++nf)
            acc[mf][nf] = (f32x4){0.f, 0.f, 0.f, 0.f};

    const int rbase = m0 + w * 32;
    int rowA0 = rbase + l15;       if (rowA0 >= M) rowA0 = M - 1;
    int rowA1 = rbase + 16 + l15;  if (rowA1 >= M) rowA1 = M - 1;
    const ushort* pa0 = Abf + (size_t)rowA0 * K + quad * 8;
    const ushort* pa1 = Abf + (size_t)rowA1 * K + quad * 8;

#pragma unroll
    for (int ks = 0; ks < K / 32; ++ks) {
        bf16x8 a0 = *(const bf16x8*)(pa0 + ks * 32);
        bf16x8 a1 = *(const bf16x8*)(pa1 + ks * 32);
        bf16x8 bfr[4];
#pragma unroll
        for (int nf = 0; nf < 4; ++nf) {
            int n = nf * 16 + l15;
            int c = (ks * 4 + quad) ^ (n & 7);
            bfr[nf] = *(const bf16x8*)&Bl[n * K + (c << 3)];
        }
#pragma unroll
        for (int nf = 0; nf < 4; ++nf) {
            acc[0][nf] = __builtin_amdgcn_mfma_f32_16x16x32_bf16(a0, bfr[nf], acc[0][nf], 0, 0, 0);
            acc[1][nf] = __builtin_amdgcn_mfma_f32_16x16x32_bf16(a1, bfr[nf], acc[1][nf], 0, 0, 0);
        }
    }

    // epilogue: bf16 store + fused fp32 logits for head `ntile`
    float as[4], ad[4];
#pragma unroll
    for (int nf = 0; nf < 4; ++nf) {
        as[nf] = a_src[ntile * HID + nf * 16 + l15];
        ad[nf] = a_dst[ntile * HID + nf * 16 + l15];
    }
#pragma unroll
    for (int mf = 0; mf < 2; ++mf) {
#pragma unroll
        for (int reg = 0; reg < 4; ++reg) {
            int row = rbase + mf * 16 + quad * 4 + reg;
            bool ok = row < M;
            if (ok) {
#pragma unroll
                for (int nf = 0; nf < 4; ++nf)
                    Cbf[(size_t)row * DTOT + n0 + nf * 16 + l15] =
                        __bfloat16_as_ushort(__float2bfloat16(acc[mf][nf][reg]));
            }
            float s0 = 0.f, d0 = 0.f;
#pragma unroll
            for (int nf = 0; nf < 4; ++nf) {
                s0 += acc[mf][nf][reg] * as[nf];
                d0 += acc[mf][nf][reg] * ad[nf];
            }
#pragma unroll
            for (int off = 1; off < 16; off <<= 1) {
                s0 += __shfl_xor(s0, off);
                d0 += __shfl_xor(d0, off);
            }
            if (ok && l15 == 0) {
                ls[row * HEADS + ntile]  = s0;
                ld_[row * HEADS + ntile] = d0;
            }
        }
    }
}

// ---------------- attention softmax per node ----------------
__global__ __launch_bounds__(256) void k_attn(const int* __restrict__ rowptr,
                                              const int* __restrict__ esrc,
                                              const float* __restrict__ ls,
                                              const float* __restrict__ ld_,
                                              float* __restrict__ attn) {
    int wave = threadIdx.x >> 6;
    int lane = threadIdx.x & 63;
    int i = blockIdx.x * 4 + wave;
    if (i >= NNODES) return;
    int h  = lane & 3;
    int eo = lane >> 2;
    int e0 = rowptr[i], e1 = rowptr[i + 1];
    float ldv = ld_[i * HEADS + h];
    float m = -INFINITY, z = 0.f;
    for (int base = e0; base < e1; base += 16) {
        int e = base + eo;
        float ev = -INFINITY;
        if (e < e1) {
            float lv = ls[esrc[e] * HEADS + h] + ldv;
            ev = lv > 0.f ? lv : ALPHA * lv;
        }
        float cm = ev;
        cm = fmaxf(cm, __shfl_xor(cm, 4));
        cm = fmaxf(cm, __shfl_xor(cm, 8));
        cm = fmaxf(cm, __shfl_xor(cm, 16));
        cm = fmaxf(cm, __shfl_xor(cm, 32));
        float nm = fmaxf(m, cm);
        float p = (e < e1) ? __expf(ev - nm) : 0.f;
        float cz = p;
        cz += __shfl_xor(cz, 4);
        cz += __shfl_xor(cz, 8);
        cz += __shfl_xor(cz, 16);
        cz += __shfl_xor(cz, 32);
        z = z * __expf(m - nm) + cz;
        m = nm;
    }
    float inv = 1.f / (z + 1e-16f);
    for (int base = e0; base < e1; base += 16) {
        int e = base + eo;
        if (e < e1) {
            float lv = ls[esrc[e] * HEADS + h] + ldv;
            float ev = lv > 0.f ? lv : ALPHA * lv;
            attn[(size_t)e * HEADS + h] = __expf(ev - m) * inv;
        }
    }
}

// ---------------- gather-aggregate + ELU ----------------
// 2 nodes/block; 128 threads/node; 2 bf16 channels/thread. BF16OUT: packed bf16 rows.
template <bool BF16OUT>
__global__ __launch_bounds__(256) void k_gather(const int* __restrict__ rowptr,
                                                const int* __restrict__ esrc,
                                                const ushort* __restrict__ Whbf,
                                                const float* __restrict__ attn,
                                                void* __restrict__ out) {
    int tid  = threadIdx.x;
    int half = tid >> 7;
    int t    = tid & 127;
    int i    = blockIdx.x * 2 + half;
    int head = t >> 5;
    int e0 = rowptr[i], e1 = rowptr[i + 1];
    float acc0 = 0.f, acc1 = 0.f;
    int e = e0;
    for (; e + 1 < e1; e += 2) {
        int s0 = esrc[e], s1 = esrc[e + 1];
        float a0 = attn[(size_t)e * HEADS + head];
        float a1 = attn[(size_t)(e + 1) * HEADS + head];
        unsigned u0 = *(const unsigned*)&Whbf[(size_t)s0 * DTOT + 2 * t];
        unsigned u1 = *(const unsigned*)&Whbf[(size_t)s1 * DTOT + 2 * t];
        acc0 = fmaf(a0, __uint_as_float(u0 << 16), acc0);
        acc1 = fmaf(a0, __uint_as_float(u0 & 0xffff0000u), acc1);
        acc0 = fmaf(a1, __uint_as_float(u1 << 16), acc0);
        acc1 = fmaf(a1, __uint_as_float(u1 & 0xffff0000u), acc1);
    }
    if (e < e1) {
        int s0 = esrc[e];
        float a0 = attn[(size_t)e * HEADS + head];
        unsigned u0 = *(const unsigned*)&Whbf[(size_t)s0 * DTOT + 2 * t];
        acc0 = fmaf(a0, __uint_as_float(u0 << 16), acc0);
        acc1 = fmaf(a0, __uint_as_float(u0 & 0xffff0000u), acc1);
    }
    float v0 = acc0 > 0.f ? acc0 : __expf(acc0) - 1.f;
    float v1 = acc1 > 0.f ? acc1 : __expf(acc1) - 1.f;
    if (BF16OUT) {
        unsigned p = (unsigned)__bfloat16_as_ushort(__float2bfloat16(v0)) |
                     ((unsigned)__bfloat16_as_ushort(__float2bfloat16(v1)) << 16);
        *(unsigned*)((ushort*)out + (size_t)i * DTOT + 2 * t) = p;
    } else {
        *(float2*)((float*)out + (size_t)i * DTOT + 2 * t) = make_float2(v0, v1);
    }
}

// ---------------- pooling (max + mean per graph) ----------------
__global__ __launch_bounds__(256) void k_pool(const float* __restrict__ h2,
                                              const int* __restrict__ gstart,
                                              float* __restrict__ pooled) {
    int g = blockIdx.x, f = threadIdx.x;
    int s = gstart[g], e = gstart[g + 1];
    float mx = -INFINITY, sm = 0.f;
    for (int n = s; n < e; ++n) {
        float v = h2[(size_t)n * DTOT + f];
        mx = fmaxf(mx, v);
        sm += v;
    }
    int cnt = e - s;
    if (cnt <= 0) mx = 0.f;
    pooled[g * 2 * DTOT + f]        = mx;
    pooled[g * 2 * DTOT + DTOT + f] = sm / (float)(cnt > 0 ? cnt : 1);
}

// ---------------- final linear (fp32 output) ----------------
__global__ __launch_bounds__(64) void k_final(const float* __restrict__ pooled,
                                              const float* __restrict__ W,
                                              const float* __restrict__ b,
                                              float* __restrict__ out) {
    int g = blockIdx.x, lane = threadIdx.x;
    for (int c = 0; c < NCLS; ++c) {
        float acc = 0.f;
        for (int k = lane; k < 2 * DTOT; k += 64)
            acc += pooled[g * 2 * DTOT + k] * W[k * NCLS + c];
#pragma unroll
        for (int off = 32; off; off >>= 1) acc += __shfl_down(acc, off);
        if (lane == 0)
            out[g * NCLS + c] = acc + b[c];
    }
}

extern "C" void kernel_launch(void* const* d_in, const int* in_sizes, int n_in,
                              void* d_out, int out_size, void* d_ws, size_t ws_size,
                              hipStream_t stream) {
    const float* x     = (const float*)d_in[0];
    const int*   ei    = (const int*)d_in[1];
    const int*   batch = (const int*)d_in[2];
    const float* W1    = (const float*)d_in[3];
    const float* a1s   = (const float*)d_in[4];
    const float* a1d   = (const float*)d_in[5];
    const float* W2    = (const float*)d_in[6];
    const float* a2s   = (const float*)d_in[7];
    const float* a2d   = (const float*)d_in[8];
    const float* linW  = (const float*)d_in[9];
    const float* linb  = (const float*)d_in[10];
    float* out = (float*)d_out;

    const int* src = ei;
    const int* dst = ei + NEDGES;

    size_t off = 0;
    char* base = (char*)d_ws;
    auto alloc = [&](size_t bytes) -> void* {
        void* p = base + off;
        off += (bytes + 255) & ~(size_t)255;
        return p;
    };
    ushort* xbf    = (ushort*)alloc((size_t)NNODES * FIN * 2);      // bf16 x   (layer-1 A)
    ushort* Whbf   = (ushort*)alloc((size_t)NNODES * DTOT * 2);     // bf16 Wh  (GEMM out, both layers)
    ushort* h1bf   = (ushort*)alloc((size_t)NNODES * DTOT * 2);     // bf16 h1  (layer-2 A)
    float*  h2     = (float*)alloc((size_t)NNODES * DTOT * 4);      // fp32 h2  (pool input)
    float*  attn   = (float*)alloc((size_t)NEDGES * HEADS * 4);
    float*  ls     = (float*)alloc((size_t)NNODES * HEADS * 4);
    float*  ld_    = (float*)alloc((size_t)NNODES * HEADS * 4);
    int*    deg    = (int*)alloc((size_t)NNODES * 4);
    int*    rowptr = (int*)alloc((size_t)(NNODES + 1) * 4);
    int*    cursor = (int*)alloc((size_t)NNODES * 4);
    int*    esrc   = (int*)alloc((size_t)NEDGES * 4);
    int*    gstart = (int*)alloc((size_t)(NGRAPH + 1) * 4);
    float*  pooled = (float*)alloc((size_t)NGRAPH * 2 * DTOT * 4);

    hipMemsetAsync(deg, 0, (size_t)NNODES * 4, stream);
    hipMemsetAsync(cursor, 0, (size_t)NNODES * 4, stream);

    int eb = (NEDGES + 255) / 256;
    int nb = (NNODES + 255) / 256;

    k_deg<<<eb, 256, 0, stream>>>(dst, deg, NEDGES);
    k_scan<<<1, 1024, 0, stream>>>(deg, rowptr, NNODES, NEDGES);
    k_fill<<<eb, 256, 0, stream>>>(src, dst, rowptr, cursor, esrc, NEDGES);
    k_gstart<<<nb, 256, 0, stream>>>(batch, gstart, NNODES);
    k_cast<<<(NNODES * FIN / 4 + 255) / 256, 256, 0, stream>>>(
        (const float4*)x, (ushort4*)xbf, NNODES * FIN / 4);

    dim3 ggrid(HEADS, (NNODES + 127) / 128);   // n-tile = one head (64 cols)

    // Layer 1
    k_gemm_mfma<FIN><<<ggrid, 256, 0, stream>>>(xbf, W1, Whbf, ls, ld_, a1s, a1d, NNODES);
    k_attn<<<(NNODES + 3) / 4, 256, 0, stream>>>(rowptr, esrc, ls, ld_, attn);
    k_gather<true><<<NNODES / 2, 256, 0, stream>>>(rowptr, esrc, Whbf, attn, h1bf);

    // Layer 2
    k_gemm_mfma<DTOT><<<ggrid, 256, 0, stream>>>(h1bf, W2, Whbf, ls, ld_, a2s, a2d, NNODES);
    k_attn<<<(NNODES + 3) / 4, 256, 0, stream>>>(rowptr, esrc, ls, ld_, attn);
    k_gather<false><<<NNODES / 2, 256, 0, stream>>>(rowptr, esrc, Whbf, attn, h2);

    // Pool + head
    k_pool<<<NGRAPH, 256, 0, stream>>>(h2, gstart, pooled);
    k_final<<<NGRAPH, 64, 0, stream>>>(pooled, linW, linb, out);
}

// Round 6
// 505.827 us; speedup vs baseline: 1.7646x; 1.1795x over previous
//
#include <hip/hip_runtime.h>
#include <hip/hip_bf16.h>

#define NNODES 50000
#define NEDGES 800000
#define FIN    128
#define HID    64
#define HEADS  4
#define NGRAPH 256
#define NCLS   10
#define DTOT   256   // HEADS*HID
#define ALPHA  0.01f

typedef short bf16x8 __attribute__((ext_vector_type(8)));
typedef float f32x4  __attribute__((ext_vector_type(4)));

// ---------------- CSR build ----------------
__global__ void k_deg(const int* __restrict__ dst, int* __restrict__ deg, int E) {
    int e = blockIdx.x * blockDim.x + threadIdx.x;
    if (e < E) atomicAdd(&deg[dst[e]], 1);
}

__global__ __launch_bounds__(1024) void k_scan(const int* __restrict__ deg,
                                               int* __restrict__ rowptr,
                                               int n, int total) {
    __shared__ int sums[1024];
    int t = threadIdx.x;
    int chunk = (n + 1023) >> 10;
    int beg = t * chunk;
    int end = beg + chunk; if (end > n) end = n;
    int s = 0;
    for (int i = beg; i < end; ++i) s += deg[i];
    sums[t] = s;
    __syncthreads();
    for (int off = 1; off < 1024; off <<= 1) {
        int v = (t >= off) ? sums[t - off] : 0;
        __syncthreads();
        sums[t] += v;
        __syncthreads();
    }
    int run = sums[t] - s;   // exclusive prefix of this chunk
    for (int i = beg; i < end; ++i) { rowptr[i] = run; run += deg[i]; }
    if (t == 1023) rowptr[n] = total;
}

__global__ void k_fill(const int* __restrict__ src, const int* __restrict__ dst,
                       const int* __restrict__ rowptr, int* __restrict__ cursor,
                       int* __restrict__ esrc, int E) {
    int e = blockIdx.x * blockDim.x + threadIdx.x;
    if (e >= E) return;
    int d = dst[e];
    int pos = rowptr[d] + atomicAdd(&cursor[d], 1);
    esrc[pos] = src[e];
}

// ---------------- graph segment starts (batch is sorted) ----------------
__global__ void k_gstart(const int* __restrict__ batch, int* __restrict__ gstart, int n) {
    int i = blockIdx.x * blockDim.x + threadIdx.x;
    if (i >= n) return;
    int b = batch[i];
    if (i == 0) {
        for (int g = 0; g <= b; ++g) gstart[g] = 0;
    } else {
        int pb = batch[i - 1];
        if (pb != b) for (int g = pb + 1; g <= b; ++g) gstart[g] = i;
    }
    if (i == n - 1) {
        for (int g = b + 1; g <= NGRAPH; ++g) gstart[g] = n;
    }
}

// ---------------- fp32 -> bf16 bulk cast ----------------
__global__ __launch_bounds__(256) void k_cast(const float4* __restrict__ in,
                                              ushort4* __restrict__ out, int n4) {
    int i = blockIdx.x * blockDim.x + threadIdx.x;
    if (i >= n4) return;
    float4 v = in[i];
    ushort4 o;
    o.x = __bfloat16_as_ushort(__float2bfloat16(v.x));
    o.y = __bfloat16_as_ushort(__float2bfloat16(v.y));
    o.z = __bfloat16_as_ushort(__float2bfloat16(v.z));
    o.w = __bfloat16_as_ushort(__float2bfloat16(v.w));
    out[i] = o;
}

// ---------------- MFMA GEMM: Cbf[M,256](bf16) = Abf[M,K](bf16) @ B[K,256](fp32->bf16) ----------------
template <int K>
__global__ __launch_bounds__(256) void k_gemm_mfma(const ushort* __restrict__ Abf,
                                                   const float* __restrict__ B,
                                                   ushort* __restrict__ Cbf,
                                                   float* __restrict__ ls,
                                                   float* __restrict__ ld_,
                                                   const float* __restrict__ a_src,
                                                   const float* __restrict__ a_dst,
                                                   int M) {
    __shared__ ushort Bl[64 * K];
    const int tid  = threadIdx.x;
    const int w    = tid >> 6;
    const int lane = tid & 63;
    const int l15  = lane & 15;
    const int quad = lane >> 4;
    const int m0    = blockIdx.y * 128;
    const int ntile = blockIdx.x;          // head index
    const int n0    = ntile * 64;

    // stage B tile (fp32 -> bf16), swizzled: element (n,k) at n*K + ((k/8 ^ (n&7))*8 + k%8)
    for (int idx = tid; idx < 64 * K; idx += 256) {
        int n = idx & 63, k = idx >> 6;
        float v = B[k * DTOT + n0 + n];
        int c = (k >> 3) ^ (n & 7);
        Bl[n * K + (c << 3) + (k & 7)] = __bfloat16_as_ushort(__float2bfloat16(v));
    }
    __syncthreads();

    f32x4 acc[2][4];
#pragma unroll
    for (int mf = 0; mf < 2; ++mf)
#pragma unroll
        for (int nf = 0; nf < 4; ++nf)
            acc[mf][nf] = (f32x4){0.f, 0.f, 0.f, 0.f};

    const int rbase = m0 + w * 32;
    int rowA0 = rbase + l15;       if (rowA0 >= M) rowA0 = M - 1;
    int rowA1 = rbase + 16 + l15;  if (rowA1 >= M) rowA1 = M - 1;
    const ushort* pa0 = Abf + (size_t)rowA0 * K + quad * 8;
    const ushort* pa1 = Abf + (size_t)rowA1 * K + quad * 8;

#pragma unroll
    for (int ks = 0; ks < K / 32; ++ks) {
        bf16x8 a0 = *(const bf16x8*)(pa0 + ks * 32);
        bf16x8 a1 = *(const bf16x8*)(pa1 + ks * 32);
        bf16x8 bfr[4];
#pragma unroll
        for (int nf = 0; nf < 4; ++nf) {
            int n = nf * 16 + l15;
            int c = (ks * 4 + quad) ^ (n & 7);
            bfr[nf] = *(const bf16x8*)&Bl[n * K + (c << 3)];
        }
#pragma unroll
        for (int nf = 0; nf < 4; ++nf) {
            acc[0][nf] = __builtin_amdgcn_mfma_f32_16x16x32_bf16(a0, bfr[nf], acc[0][nf], 0, 0, 0);
            acc[1][nf] = __builtin_amdgcn_mfma_f32_16x16x32_bf16(a1, bfr[nf], acc[1][nf], 0, 0, 0);
        }
    }

    // epilogue: bf16 store + fused fp32 logits for head `ntile`
    float as[4], ad[4];
#pragma unroll
    for (int nf = 0; nf < 4; ++nf) {
        as[nf] = a_src[ntile * HID + nf * 16 + l15];
        ad[nf] = a_dst[ntile * HID + nf * 16 + l15];
    }
#pragma unroll
    for (int mf = 0; mf < 2; ++mf) {
#pragma unroll
        for (int reg = 0; reg < 4; ++reg) {
            int row = rbase + mf * 16 + quad * 4 + reg;
            bool ok = row < M;
            if (ok) {
#pragma unroll
                for (int nf = 0; nf < 4; ++nf)
                    Cbf[(size_t)row * DTOT + n0 + nf * 16 + l15] =
                        __bfloat16_as_ushort(__float2bfloat16(acc[mf][nf][reg]));
            }
            float s0 = 0.f, d0 = 0.f;
#pragma unroll
            for (int nf = 0; nf < 4; ++nf) {
                s0 += acc[mf][nf][reg] * as[nf];
                d0 += acc[mf][nf][reg] * ad[nf];
            }
#pragma unroll
            for (int off = 1; off < 16; off <<= 1) {
                s0 += __shfl_xor(s0, off);
                d0 += __shfl_xor(d0, off);
            }
            if (ok && l15 == 0) {
                ls[row * HEADS + ntile]  = s0;
                ld_[row * HEADS + ntile] = d0;
            }
        }
    }
}

// ---------------- fused softmax + gather-aggregate + ELU ----------------
// One wave per node (4 nodes / 256-block). Lane handles 4 bf16 channels (8B loads);
// head = lane>>4. Pass A: group-max of ls over sources (lrelu is monotone, so
// max_e lrelu(ls+ld) = lrelu(max ls + ld)). Pass B: single fused pass computing
// p = exp(e - M) inline, accumulating p*row and z (z identical in all lanes).
template <bool BF16OUT>
__global__ __launch_bounds__(256) void k_gat_aggr(const int* __restrict__ rowptr,
                                                  const int* __restrict__ esrc,
                                                  const ushort* __restrict__ Whbf,
                                                  const float* __restrict__ ls,
                                                  const float* __restrict__ ld_,
                                                  void* __restrict__ out) {
    const int wv   = threadIdx.x >> 6;
    const int lane = threadIdx.x & 63;
    const int i    = blockIdx.x * 4 + wv;
    if (i >= NNODES) return;
    const int h  = lane >> 4;      // head
    const int gl = lane & 15;      // lane within head group
    const int e0 = rowptr[i], e1 = rowptr[i + 1];
    const float ldv = ld_[i * HEADS + h];

    // ---- pass A: M = lrelu(max_s ls[s,h] + ldv) ----
    float mx = -INFINITY;
    for (int e = e0 + gl; e < e1; e += 16)
        mx = fmaxf(mx, ls[esrc[e] * HEADS + h]);
    mx = fmaxf(mx, __shfl_xor(mx, 1));
    mx = fmaxf(mx, __shfl_xor(mx, 2));
    mx = fmaxf(mx, __shfl_xor(mx, 4));
    mx = fmaxf(mx, __shfl_xor(mx, 8));
    float lvm = mx + ldv;
    const float M = lvm > 0.f ? lvm : ALPHA * lvm;

    // ---- pass B: fused exp + weighted gather ----
    float a0 = 0.f, a1 = 0.f, a2 = 0.f, a3 = 0.f, z = 0.f;
    const int ch = 4 * lane;
    int e = e0;
    for (; e + 3 < e1; e += 4) {
        int s0 = esrc[e], s1 = esrc[e + 1], s2 = esrc[e + 2], s3 = esrc[e + 3];
        float l0 = ls[s0 * HEADS + h] + ldv;
        float l1 = ls[s1 * HEADS + h] + ldv;
        float l2 = ls[s2 * HEADS + h] + ldv;
        float l3 = ls[s3 * HEADS + h] + ldv;
        uint2 u0 = *(const uint2*)&Whbf[(size_t)s0 * DTOT + ch];
        uint2 u1 = *(const uint2*)&Whbf[(size_t)s1 * DTOT + ch];
        uint2 u2 = *(const uint2*)&Whbf[(size_t)s2 * DTOT + ch];
        uint2 u3 = *(const uint2*)&Whbf[(size_t)s3 * DTOT + ch];
        float p0 = __expf((l0 > 0.f ? l0 : ALPHA * l0) - M);
        float p1 = __expf((l1 > 0.f ? l1 : ALPHA * l1) - M);
        float p2 = __expf((l2 > 0.f ? l2 : ALPHA * l2) - M);
        float p3 = __expf((l3 > 0.f ? l3 : ALPHA * l3) - M);
        z += p0 + p1 + p2 + p3;
        a0 = fmaf(p0, __uint_as_float(u0.x << 16), a0);
        a1 = fmaf(p0, __uint_as_float(u0.x & 0xffff0000u), a1);
        a2 = fmaf(p0, __uint_as_float(u0.y << 16), a2);
        a3 = fmaf(p0, __uint_as_float(u0.y & 0xffff0000u), a3);
        a0 = fmaf(p1, __uint_as_float(u1.x << 16), a0);
        a1 = fmaf(p1, __uint_as_float(u1.x & 0xffff0000u), a1);
        a2 = fmaf(p1, __uint_as_float(u1.y << 16), a2);
        a3 = fmaf(p1, __uint_as_float(u1.y & 0xffff0000u), a3);
        a0 = fmaf(p2, __uint_as_float(u2.x << 16), a0);
        a1 = fmaf(p2, __uint_as_float(u2.x & 0xffff0000u), a1);
        a2 = fmaf(p2, __uint_as_float(u2.y << 16), a2);
        a3 = fmaf(p2, __uint_as_float(u2.y & 0xffff0000u), a3);
        a0 = fmaf(p3, __uint_as_float(u3.x << 16), a0);
        a1 = fmaf(p3, __uint_as_float(u3.x & 0xffff0000u), a1);
        a2 = fmaf(p3, __uint_as_float(u3.y << 16), a2);
        a3 = fmaf(p3, __uint_as_float(u3.y & 0xffff0000u), a3);
    }
    for (; e < e1; ++e) {
        int s0 = esrc[e];
        float l0 = ls[s0 * HEADS + h] + ldv;
        uint2 u0 = *(const uint2*)&Whbf[(size_t)s0 * DTOT + ch];
        float p0 = __expf((l0 > 0.f ? l0 : ALPHA * l0) - M);
        z += p0;
        a0 = fmaf(p0, __uint_as_float(u0.x << 16), a0);
        a1 = fmaf(p0, __uint_as_float(u0.x & 0xffff0000u), a1);
        a2 = fmaf(p0, __uint_as_float(u0.y << 16), a2);
        a3 = fmaf(p0, __uint_as_float(u0.y & 0xffff0000u), a3);
    }

    const float inv = 1.f / (z + 1e-16f);
    float v0 = a0 * inv, v1 = a1 * inv, v2 = a2 * inv, v3 = a3 * inv;
    v0 = v0 > 0.f ? v0 : __expf(v0) - 1.f;
    v1 = v1 > 0.f ? v1 : __expf(v1) - 1.f;
    v2 = v2 > 0.f ? v2 : __expf(v2) - 1.f;
    v3 = v3 > 0.f ? v3 : __expf(v3) - 1.f;
    if (BF16OUT) {
        ushort4 pk;
        pk.x = __bfloat16_as_ushort(__float2bfloat16(v0));
        pk.y = __bfloat16_as_ushort(__float2bfloat16(v1));
        pk.z = __bfloat16_as_ushort(__float2bfloat16(v2));
        pk.w = __bfloat16_as_ushort(__float2bfloat16(v3));
        *(ushort4*)((ushort*)out + (size_t)i * DTOT + ch) = pk;
    } else {
        *(float4*)((float*)out + (size_t)i * DTOT + ch) = make_float4(v0, v1, v2, v3);
    }
}

// ---------------- pooling (max + mean per graph) ----------------
__global__ __launch_bounds__(256) void k_pool(const float* __restrict__ h2,
                                              const int* __restrict__ gstart,
                                              float* __restrict__ pooled) {
    int g = blockIdx.x, f = threadIdx.x;
    int s = gstart[g], e = gstart[g + 1];
    float mx = -INFINITY, sm = 0.f;
    for (int n = s; n < e; ++n) {
        float v = h2[(size_t)n * DTOT + f];
        mx = fmaxf(mx, v);
        sm += v;
    }
    int cnt = e - s;
    if (cnt <= 0) mx = 0.f;
    pooled[g * 2 * DTOT + f]        = mx;
    pooled[g * 2 * DTOT + DTOT + f] = sm / (float)(cnt > 0 ? cnt : 1);
}

// ---------------- final linear (fp32 output) ----------------
__global__ __launch_bounds__(64) void k_final(const float* __restrict__ pooled,
                                              const float* __restrict__ W,
                                              const float* __restrict__ b,
                                              float* __restrict__ out) {
    int g = blockIdx.x, lane = threadIdx.x;
    for (int c = 0; c < NCLS; ++c) {
        float acc = 0.f;
        for (int k = lane; k < 2 * DTOT; k += 64)
            acc += pooled[g * 2 * DTOT + k] * W[k * NCLS + c];
#pragma unroll
        for (int off = 32; off; off >>= 1) acc += __shfl_down(acc, off);
        if (lane == 0)
            out[g * NCLS + c] = acc + b[c];
    }
}

extern "C" void kernel_launch(void* const* d_in, const int* in_sizes, int n_in,
                              void* d_out, int out_size, void* d_ws, size_t ws_size,
                              hipStream_t stream) {
    const float* x     = (const float*)d_in[0];
    const int*   ei    = (const int*)d_in[1];
    const int*   batch = (const int*)d_in[2];
    const float* W1    = (const float*)d_in[3];
    const float* a1s   = (const float*)d_in[4];
    const float* a1d   = (const float*)d_in[5];
    const float* W2    = (const float*)d_in[6];
    const float* a2s   = (const float*)d_in[7];
    const float* a2d   = (const float*)d_in[8];
    const float* linW  = (const float*)d_in[9];
    const float* linb  = (const float*)d_in[10];
    float* out = (float*)d_out;

    const int* src = ei;
    const int* dst = ei + NEDGES;

    size_t off = 0;
    char* base = (char*)d_ws;
    auto alloc = [&](size_t bytes) -> void* {
        void* p = base + off;
        off += (bytes + 255) & ~(size_t)255;
        return p;
    };
    ushort* xbf    = (ushort*)alloc((size_t)NNODES * FIN * 2);      // bf16 x   (layer-1 A)
    ushort* Whbf   = (ushort*)alloc((size_t)NNODES * DTOT * 2);     // bf16 Wh  (GEMM out, both layers)
    ushort* h1bf   = (ushort*)alloc((size_t)NNODES * DTOT * 2);     // bf16 h1  (layer-2 A)
    float*  h2     = (float*)alloc((size_t)NNODES * DTOT * 4);      // fp32 h2  (pool input)
    float*  ls     = (float*)alloc((size_t)NNODES * HEADS * 4);
    float*  ld_    = (float*)alloc((size_t)NNODES * HEADS * 4);
    int*    deg    = (int*)alloc((size_t)NNODES * 4);
    int*    rowptr = (int*)alloc((size_t)(NNODES + 1) * 4);
    int*    cursor = (int*)alloc((size_t)NNODES * 4);
    int*    esrc   = (int*)alloc((size_t)NEDGES * 4);
    int*    gstart = (int*)alloc((size_t)(NGRAPH + 1) * 4);
    float*  pooled = (float*)alloc((size_t)NGRAPH * 2 * DTOT * 4);

    hipMemsetAsync(deg, 0, (size_t)NNODES * 4, stream);
    hipMemsetAsync(cursor, 0, (size_t)NNODES * 4, stream);

    int eb = (NEDGES + 255) / 256;
    int nb = (NNODES + 255) / 256;

    k_deg<<<eb, 256, 0, stream>>>(dst, deg, NEDGES);
    k_scan<<<1, 1024, 0, stream>>>(deg, rowptr, NNODES, NEDGES);
    k_fill<<<eb, 256, 0, stream>>>(src, dst, rowptr, cursor, esrc, NEDGES);
    k_gstart<<<nb, 256, 0, stream>>>(batch, gstart, NNODES);
    k_cast<<<(NNODES * FIN / 4 + 255) / 256, 256, 0, stream>>>(
        (const float4*)x, (ushort4*)xbf, NNODES * FIN / 4);

    dim3 ggrid(HEADS, (NNODES + 127) / 128);   // n-tile = one head (64 cols)

    // Layer 1
    k_gemm_mfma<FIN><<<ggrid, 256, 0, stream>>>(xbf, W1, Whbf, ls, ld_, a1s, a1d, NNODES);
    k_gat_aggr<true><<<(NNODES + 3) / 4, 256, 0, stream>>>(rowptr, esrc, Whbf, ls, ld_, h1bf);

    // Layer 2
    k_gemm_mfma<DTOT><<<ggrid, 256, 0, stream>>>(h1bf, W2, Whbf, ls, ld_, a2s, a2d, NNODES);
    k_gat_aggr<false><<<(NNODES + 3) / 4, 256, 0, stream>>>(rowptr, esrc, Whbf, ls, ld_, h2);

    // Pool + head
    k_pool<<<NGRAPH, 256, 0, stream>>>(h2, gstart, pooled);
    k_final<<<NGRAPH, 64, 0, stream>>>(pooled, linW, linb, out);
}

// Round 7
// 433.448 us; speedup vs baseline: 2.0593x; 1.1670x over previous
//
#include <hip/hip_runtime.h>
#include <hip/hip_bf16.h>

#define NNODES 50000
#define NEDGES 800000
#define FIN    128
#define HID    64
#define HEADS  4
#define NGRAPH 256
#define NCLS   10
#define DTOT   256   // HEADS*HID
#define ALPHA  0.01f

typedef short bf16x8 __attribute__((ext_vector_type(8)));
typedef float f32x4  __attribute__((ext_vector_type(4)));

#define SCAN_NB ((NNODES + 255) / 256)   // 196 blocks in hierarchical scan

// ---------------- CSR build ----------------
__global__ void k_deg(const int* __restrict__ dst, int* __restrict__ deg, int E) {
    int e = blockIdx.x * blockDim.x + threadIdx.x;
    if (e < E) atomicAdd(&deg[dst[e]], 1);
}

// Phase A: per-block exclusive scan (256 elems) + block totals.
__global__ __launch_bounds__(256) void k_scan_blk(const int* __restrict__ deg,
                                                  int* __restrict__ rowptr,
                                                  int* __restrict__ bsum, int n) {
    __shared__ int wsum[4];
    int t = threadIdx.x;
    int i = blockIdx.x * 256 + t;
    int lane = t & 63, w = t >> 6;
    int v = (i < n) ? deg[i] : 0;
    int s = v;
#pragma unroll
    for (int off = 1; off < 64; off <<= 1) {
        int u = __shfl_up(s, off);
        if (lane >= off) s += u;
    }
    if (lane == 63) wsum[w] = s;
    __syncthreads();
    int add = 0;
#pragma unroll
    for (int j = 0; j < 3; ++j) add += (j < w) ? wsum[j] : 0;
    int incl = s + add;
    if (i < n) rowptr[i] = incl - v;           // exclusive, pre-offset
    if (t == 255) bsum[blockIdx.x] = incl;     // block total
}

// Phase B: scan the block sums (SCAN_NB <= 256) into exclusive offsets.
__global__ __launch_bounds__(256) void k_scan_top(const int* __restrict__ bsum,
                                                  int* __restrict__ boff, int nb) {
    __shared__ int wsum[4];
    int t = threadIdx.x, lane = t & 63, w = t >> 6;
    int v = (t < nb) ? bsum[t] : 0;
    int s = v;
#pragma unroll
    for (int off = 1; off < 64; off <<= 1) {
        int u = __shfl_up(s, off);
        if (lane >= off) s += u;
    }
    if (lane == 63) wsum[w] = s;
    __syncthreads();
    int add = 0;
#pragma unroll
    for (int j = 0; j < 3; ++j) add += (j < w) ? wsum[j] : 0;
    boff[t] = s + add - v;                     // exclusive
}

// Phase C: add block offsets; write sentinel rowptr[n] = total.
__global__ __launch_bounds__(256) void k_scan_add(int* __restrict__ rowptr,
                                                  const int* __restrict__ boff,
                                                  int n, int total) {
    int i = blockIdx.x * 256 + threadIdx.x;
    if (i < n) rowptr[i] += boff[i >> 8];
    else if (i == n) rowptr[n] = total;
}

__global__ void k_fill(const int* __restrict__ src, const int* __restrict__ dst,
                       const int* __restrict__ rowptr, int* __restrict__ cursor,
                       int* __restrict__ esrc, int E) {
    int e = blockIdx.x * blockDim.x + threadIdx.x;
    if (e >= E) return;
    int d = dst[e];
    int pos = rowptr[d] + atomicAdd(&cursor[d], 1);
    esrc[pos] = src[e];
}

// ---------------- graph segment starts (batch is sorted) ----------------
__global__ void k_gstart(const int* __restrict__ batch, int* __restrict__ gstart, int n) {
    int i = blockIdx.x * blockDim.x + threadIdx.x;
    if (i >= n) return;
    int b = batch[i];
    if (i == 0) {
        for (int g = 0; g <= b; ++g) gstart[g] = 0;
    } else {
        int pb = batch[i - 1];
        if (pb != b) for (int g = pb + 1; g <= b; ++g) gstart[g] = i;
    }
    if (i == n - 1) {
        for (int g = b + 1; g <= NGRAPH; ++g) gstart[g] = n;
    }
}

// ---------------- fp32 -> bf16 bulk cast ----------------
__global__ __launch_bounds__(256) void k_cast(const float4* __restrict__ in,
                                              ushort4* __restrict__ out, int n4) {
    int i = blockIdx.x * blockDim.x + threadIdx.x;
    if (i >= n4) return;
    float4 v = in[i];
    ushort4 o;
    o.x = __bfloat16_as_ushort(__float2bfloat16(v.x));
    o.y = __bfloat16_as_ushort(__float2bfloat16(v.y));
    o.z = __bfloat16_as_ushort(__float2bfloat16(v.z));
    o.w = __bfloat16_as_ushort(__float2bfloat16(v.w));
    out[i] = o;
}

// ---------------- MFMA GEMM: Cbf[M,256](bf16) = Abf[M,K](bf16) @ B[K,256](fp32->bf16) ----------------
template <int K>
__global__ __launch_bounds__(256) void k_gemm_mfma(const ushort* __restrict__ Abf,
                                                   const float* __restrict__ B,
                                                   ushort* __restrict__ Cbf,
                                                   float* __restrict__ ls,
                                                   float* __restrict__ ld_,
                                                   const float* __restrict__ a_src,
                                                   const float* __restrict__ a_dst,
                                                   int M) {
    __shared__ ushort Bl[64 * K];
    const int tid  = threadIdx.x;
    const int w    = tid >> 6;
    const int lane = tid & 63;
    const int l15  = lane & 15;
    const int quad = lane >> 4;
    const int m0    = blockIdx.y * 128;
    const int ntile = blockIdx.x;          // head index
    const int n0    = ntile * 64;

    // stage B tile (fp32 -> bf16), swizzled: element (n,k) at n*K + ((k/8 ^ (n&7))*8 + k%8)
    for (int idx = tid; idx < 64 * K; idx += 256) {
        int n = idx & 63, k = idx >> 6;
        float v = B[k * DTOT + n0 + n];
        int c = (k >> 3) ^ (n & 7);
        Bl[n * K + (c << 3) + (k & 7)] = __bfloat16_as_ushort(__float2bfloat16(v));
    }
    __syncthreads();

    f32x4 acc[2][4];
#pragma unroll
    for (int mf = 0; mf < 2; ++mf)
#pragma unroll
        for (int nf = 0; nf < 4; ++nf)
            acc[mf][nf] = (f32x4){0.f, 0.f, 0.f, 0.f};

    const int rbase = m0 + w * 32;
    int rowA0 = rbase + l15;       if (rowA0 >= M) rowA0 = M - 1;
    int rowA1 = rbase + 16 + l15;  if (rowA1 >= M) rowA1 = M - 1;
    const ushort* pa0 = Abf + (size_t)rowA0 * K + quad * 8;
    const ushort* pa1 = Abf + (size_t)rowA1 * K + quad * 8;

#pragma unroll
    for (int ks = 0; ks < K / 32; ++ks) {
        bf16x8 a0 = *(const bf16x8*)(pa0 + ks * 32);
        bf16x8 a1 = *(const bf16x8*)(pa1 + ks * 32);
        bf16x8 bfr[4];
#pragma unroll
        for (int nf = 0; nf < 4; ++nf) {
            int n = nf * 16 + l15;
            int c = (ks * 4 + quad) ^ (n & 7);
            bfr[nf] = *(const bf16x8*)&Bl[n * K + (c << 3)];
        }
#pragma unroll
        for (int nf = 0; nf < 4; ++nf) {
            acc[0][nf] = __builtin_amdgcn_mfma_f32_16x16x32_bf16(a0, bfr[nf], acc[0][nf], 0, 0, 0);
            acc[1][nf] = __builtin_amdgcn_mfma_f32_16x16x32_bf16(a1, bfr[nf], acc[1][nf], 0, 0, 0);
        }
    }

    // epilogue: bf16 store + fused fp32 logits for head `ntile`
    float as[4], ad[4];
#pragma unroll
    for (int nf = 0; nf < 4; ++nf) {
        as[nf] = a_src[ntile * HID + nf * 16 + l15];
        ad[nf] = a_dst[ntile * HID + nf * 16 + l15];
    }
#pragma unroll
    for (int mf = 0; mf < 2; ++mf) {
#pragma unroll
        for (int reg = 0; reg < 4; ++reg) {
            int row = rbase + mf * 16 + quad * 4 + reg;
            bool ok = row < M;
            if (ok) {
#pragma unroll
                for (int nf = 0; nf < 4; ++nf)
                    Cbf[(size_t)row * DTOT + n0 + nf * 16 + l15] =
                        __bfloat16_as_ushort(__float2bfloat16(acc[mf][nf][reg]));
            }
            float s0 = 0.f, d0 = 0.f;
#pragma unroll
            for (int nf = 0; nf < 4; ++nf) {
                s0 += acc[mf][nf][reg] * as[nf];
                d0 += acc[mf][nf][reg] * ad[nf];
            }
#pragma unroll
            for (int off = 1; off < 16; off <<= 1) {
                s0 += __shfl_xor(s0, off);
                d0 += __shfl_xor(d0, off);
            }
            if (ok && l15 == 0) {
                ls[row * HEADS + ntile]  = s0;
                ld_[row * HEADS + ntile] = d0;
            }
        }
    }
}

// ---------------- fused softmax + gather-aggregate + ELU ----------------
template <bool BF16OUT>
__global__ __launch_bounds__(256) void k_gat_aggr(const int* __restrict__ rowptr,
                                                  const int* __restrict__ esrc,
                                                  const ushort* __restrict__ Whbf,
                                                  const float* __restrict__ ls,
                                                  const float* __restrict__ ld_,
                                                  void* __restrict__ out) {
    const int wv   = threadIdx.x >> 6;
    const int lane = threadIdx.x & 63;
    const int i    = blockIdx.x * 4 + wv;
    if (i >= NNODES) return;
    const int h  = lane >> 4;      // head
    const int gl = lane & 15;      // lane within head group
    const int e0 = rowptr[i], e1 = rowptr[i + 1];
    const float ldv = ld_[i * HEADS + h];

    // ---- pass A: M = lrelu(max_s ls[s,h] + ldv) ----
    float mx = -INFINITY;
    for (int e = e0 + gl; e < e1; e += 16)
        mx = fmaxf(mx, ls[esrc[e] * HEADS + h]);
    mx = fmaxf(mx, __shfl_xor(mx, 1));
    mx = fmaxf(mx, __shfl_xor(mx, 2));
    mx = fmaxf(mx, __shfl_xor(mx, 4));
    mx = fmaxf(mx, __shfl_xor(mx, 8));
    float lvm = mx + ldv;
    const float M = lvm > 0.f ? lvm : ALPHA * lvm;

    // ---- pass B: fused exp + weighted gather ----
    float a0 = 0.f, a1 = 0.f, a2 = 0.f, a3 = 0.f, z = 0.f;
    const int ch = 4 * lane;
    int e = e0;
    for (; e + 3 < e1; e += 4) {
        int s0 = esrc[e], s1 = esrc[e + 1], s2 = esrc[e + 2], s3 = esrc[e + 3];
        float l0 = ls[s0 * HEADS + h] + ldv;
        float l1 = ls[s1 * HEADS + h] + ldv;
        float l2 = ls[s2 * HEADS + h] + ldv;
        float l3 = ls[s3 * HEADS + h] + ldv;
        uint2 u0 = *(const uint2*)&Whbf[(size_t)s0 * DTOT + ch];
        uint2 u1 = *(const uint2*)&Whbf[(size_t)s1 * DTOT + ch];
        uint2 u2 = *(const uint2*)&Whbf[(size_t)s2 * DTOT + ch];
        uint2 u3 = *(const uint2*)&Whbf[(size_t)s3 * DTOT + ch];
        float p0 = __expf((l0 > 0.f ? l0 : ALPHA * l0) - M);
        float p1 = __expf((l1 > 0.f ? l1 : ALPHA * l1) - M);
        float p2 = __expf((l2 > 0.f ? l2 : ALPHA * l2) - M);
        float p3 = __expf((l3 > 0.f ? l3 : ALPHA * l3) - M);
        z += p0 + p1 + p2 + p3;
        a0 = fmaf(p0, __uint_as_float(u0.x << 16), a0);
        a1 = fmaf(p0, __uint_as_float(u0.x & 0xffff0000u), a1);
        a2 = fmaf(p0, __uint_as_float(u0.y << 16), a2);
        a3 = fmaf(p0, __uint_as_float(u0.y & 0xffff0000u), a3);
        a0 = fmaf(p1, __uint_as_float(u1.x << 16), a0);
        a1 = fmaf(p1, __uint_as_float(u1.x & 0xffff0000u), a1);
        a2 = fmaf(p1, __uint_as_float(u1.y << 16), a2);
        a3 = fmaf(p1, __uint_as_float(u1.y & 0xffff0000u), a3);
        a0 = fmaf(p2, __uint_as_float(u2.x << 16), a0);
        a1 = fmaf(p2, __uint_as_float(u2.x & 0xffff0000u), a1);
        a2 = fmaf(p2, __uint_as_float(u2.y << 16), a2);
        a3 = fmaf(p2, __uint_as_float(u2.y & 0xffff0000u), a3);
        a0 = fmaf(p3, __uint_as_float(u3.x << 16), a0);
        a1 = fmaf(p3, __uint_as_float(u3.x & 0xffff0000u), a1);
        a2 = fmaf(p3, __uint_as_float(u3.y << 16), a2);
        a3 = fmaf(p3, __uint_as_float(u3.y & 0xffff0000u), a3);
    }
    for (; e < e1; ++e) {
        int s0 = esrc[e];
        float l0 = ls[s0 * HEADS + h] + ldv;
        uint2 u0 = *(const uint2*)&Whbf[(size_t)s0 * DTOT + ch];
        float p0 = __expf((l0 > 0.f ? l0 : ALPHA * l0) - M);
        z += p0;
        a0 = fmaf(p0, __uint_as_float(u0.x << 16), a0);
        a1 = fmaf(p0, __uint_as_float(u0.x & 0xffff0000u), a1);
        a2 = fmaf(p0, __uint_as_float(u0.y << 16), a2);
        a3 = fmaf(p0, __uint_as_float(u0.y & 0xffff0000u), a3);
    }

    const float inv = 1.f / (z + 1e-16f);
    float v0 = a0 * inv, v1 = a1 * inv, v2 = a2 * inv, v3 = a3 * inv;
    v0 = v0 > 0.f ? v0 : __expf(v0) - 1.f;
    v1 = v1 > 0.f ? v1 : __expf(v1) - 1.f;
    v2 = v2 > 0.f ? v2 : __expf(v2) - 1.f;
    v3 = v3 > 0.f ? v3 : __expf(v3) - 1.f;
    if (BF16OUT) {
        ushort4 pk;
        pk.x = __bfloat16_as_ushort(__float2bfloat16(v0));
        pk.y = __bfloat16_as_ushort(__float2bfloat16(v1));
        pk.z = __bfloat16_as_ushort(__float2bfloat16(v2));
        pk.w = __bfloat16_as_ushort(__float2bfloat16(v3));
        *(ushort4*)((ushort*)out + (size_t)i * DTOT + ch) = pk;
    } else {
        *(float4*)((float*)out + (size_t)i * DTOT + ch) = make_float4(v0, v1, v2, v3);
    }
}

// ---------------- pooling (max + mean per graph) ----------------
__global__ __launch_bounds__(256) void k_pool(const float* __restrict__ h2,
                                              const int* __restrict__ gstart,
                                              float* __restrict__ pooled) {
    int g = blockIdx.x, f = threadIdx.x;
    int s = gstart[g], e = gstart[g + 1];
    float mx = -INFINITY, sm = 0.f;
    for (int n = s; n < e; ++n) {
        float v = h2[(size_t)n * DTOT + f];
        mx = fmaxf(mx, v);
        sm += v;
    }
    int cnt = e - s;
    if (cnt <= 0) mx = 0.f;
    pooled[g * 2 * DTOT + f]        = mx;
    pooled[g * 2 * DTOT + DTOT + f] = sm / (float)(cnt > 0 ? cnt : 1);
}

// ---------------- final linear (fp32 output) ----------------
__global__ __launch_bounds__(64) void k_final(const float* __restrict__ pooled,
                                              const float* __restrict__ W,
                                              const float* __restrict__ b,
                                              float* __restrict__ out) {
    int g = blockIdx.x, lane = threadIdx.x;
    for (int c = 0; c < NCLS; ++c) {
        float acc = 0.f;
        for (int k = lane; k < 2 * DTOT; k += 64)
            acc += pooled[g * 2 * DTOT + k] * W[k * NCLS + c];
#pragma unroll
        for (int off = 32; off; off >>= 1) acc += __shfl_down(acc, off);
        if (lane == 0)
            out[g * NCLS + c] = acc + b[c];
    }
}

extern "C" void kernel_launch(void* const* d_in, const int* in_sizes, int n_in,
                              void* d_out, int out_size, void* d_ws, size_t ws_size,
                              hipStream_t stream) {
    const float* x     = (const float*)d_in[0];
    const int*   ei    = (const int*)d_in[1];
    const int*   batch = (const int*)d_in[2];
    const float* W1    = (const float*)d_in[3];
    const float* a1s   = (const float*)d_in[4];
    const float* a1d   = (const float*)d_in[5];
    const float* W2    = (const float*)d_in[6];
    const float* a2s   = (const float*)d_in[7];
    const float* a2d   = (const float*)d_in[8];
    const float* linW  = (const float*)d_in[9];
    const float* linb  = (const float*)d_in[10];
    float* out = (float*)d_out;

    const int* src = ei;
    const int* dst = ei + NEDGES;

    size_t off = 0;
    char* base = (char*)d_ws;
    auto alloc = [&](size_t bytes) -> void* {
        void* p = base + off;
        off += (bytes + 255) & ~(size_t)255;
        return p;
    };
    ushort* xbf    = (ushort*)alloc((size_t)NNODES * FIN * 2);      // bf16 x   (layer-1 A)
    ushort* Whbf   = (ushort*)alloc((size_t)NNODES * DTOT * 2);     // bf16 Wh  (GEMM out, both layers)
    ushort* h1bf   = (ushort*)alloc((size_t)NNODES * DTOT * 2);     // bf16 h1  (layer-2 A)
    float*  h2     = (float*)alloc((size_t)NNODES * DTOT * 4);      // fp32 h2  (pool input)
    float*  ls     = (float*)alloc((size_t)NNODES * HEADS * 4);
    float*  ld_    = (float*)alloc((size_t)NNODES * HEADS * 4);
    int*    deg    = (int*)alloc((size_t)NNODES * 4);
    int*    rowptr = (int*)alloc((size_t)(NNODES + 1) * 4);
    int*    cursor = (int*)alloc((size_t)NNODES * 4);
    int*    esrc   = (int*)alloc((size_t)NEDGES * 4);
    int*    gstart = (int*)alloc((size_t)(NGRAPH + 1) * 4);
    float*  pooled = (float*)alloc((size_t)NGRAPH * 2 * DTOT * 4);
    int*    bsum   = (int*)alloc((size_t)SCAN_NB * 4);
    int*    boff   = (int*)alloc((size_t)256 * 4);

    hipMemsetAsync(deg, 0, (size_t)NNODES * 4, stream);
    hipMemsetAsync(cursor, 0, (size_t)NNODES * 4, stream);

    int eb = (NEDGES + 255) / 256;
    int nb = (NNODES + 255) / 256;

    k_deg<<<eb, 256, 0, stream>>>(dst, deg, NEDGES);
    k_scan_blk<<<SCAN_NB, 256, 0, stream>>>(deg, rowptr, bsum, NNODES);
    k_scan_top<<<1, 256, 0, stream>>>(bsum, boff, SCAN_NB);
    k_scan_add<<<(NNODES + 256) / 256, 256, 0, stream>>>(rowptr, boff, NNODES, NEDGES);
    k_fill<<<eb, 256, 0, stream>>>(src, dst, rowptr, cursor, esrc, NEDGES);
    k_gstart<<<nb, 256, 0, stream>>>(batch, gstart, NNODES);
    k_cast<<<(NNODES * FIN / 4 + 255) / 256, 256, 0, stream>>>(
        (const float4*)x, (ushort4*)xbf, NNODES * FIN / 4);

    dim3 ggrid(HEADS, (NNODES + 127) / 128);   // n-tile = one head (64 cols)

    // Layer 1
    k_gemm_mfma<FIN><<<ggrid, 256, 0, stream>>>(xbf, W1, Whbf, ls, ld_, a1s, a1d, NNODES);
    k_gat_aggr<true><<<(NNODES + 3) / 4, 256, 0, stream>>>(rowptr, esrc, Whbf, ls, ld_, h1bf);

    // Layer 2
    k_gemm_mfma<DTOT><<<ggrid, 256, 0, stream>>>(h1bf, W2, Whbf, ls, ld_, a2s, a2d, NNODES);
    k_gat_aggr<false><<<(NNODES + 3) / 4, 256, 0, stream>>>(rowptr, esrc, Whbf, ls, ld_, h2);

    // Pool + head
    k_pool<<<NGRAPH, 256, 0, stream>>>(h2, gstart, pooled);
    k_final<<<NGRAPH, 64, 0, stream>>>(pooled, linW, linb, out);
}

// Round 8
// 421.912 us; speedup vs baseline: 2.1156x; 1.0273x over previous
//
#include <hip/hip_runtime.h>
#include <hip/hip_bf16.h>

#define NNODES 50000
#define NEDGES 800000
#define FIN    128
#define HID    64
#define HEADS  4
#define NGRAPH 256
#define NCLS   10
#define DTOT   256   // HEADS*HID
#define ALPHA  0.01f

typedef short bf16x8 __attribute__((ext_vector_type(8)));
typedef float f32x4  __attribute__((ext_vector_type(4)));

#define SCAN_NB ((NNODES + 255) / 256)      // 196
#define EB      ((NEDGES + 255) / 256)      // 3125
#define XB      ((NNODES * FIN / 4 + 255) / 256)  // 6250
#define W1B     (FIN * DTOT / 256)          // 128
#define W2B     (DTOT * DTOT / 256)         // 256

__device__ __forceinline__ ushort f2bf(float v) {
    return __bfloat16_as_ushort(__float2bfloat16(v));
}
__device__ __forceinline__ float blo(unsigned u) { return __uint_as_float(u << 16); }
__device__ __forceinline__ float bhi(unsigned u) { return __uint_as_float(u & 0xffff0000u); }

// ---------------- fused setup: deg histogram | gstart | cast x | transpose W1,W2 ----------------
// W transposes bake the GEMM LDS layout: Wt[n*K + ((k/8 ^ (n&7))*8) + k%8] = bf16(W[k*DTOT+n])
__global__ __launch_bounds__(256) void k_setup(const int* __restrict__ dst, int* __restrict__ deg,
                                               const int* __restrict__ batch, int* __restrict__ gstart,
                                               const float4* __restrict__ x4, ushort4* __restrict__ xbf4,
                                               const float* __restrict__ W1, ushort* __restrict__ W1t,
                                               const float* __restrict__ W2, ushort* __restrict__ W2t) {
    int b = blockIdx.x, t = threadIdx.x;
    if (b < EB) {
        int e = b * 256 + t;
        if (e < NEDGES) atomicAdd(&deg[dst[e]], 1);
    } else if (b < EB + SCAN_NB) {
        int i = (b - EB) * 256 + t;
        if (i >= NNODES) return;
        int bb = batch[i];
        if (i == 0) {
            for (int g = 0; g <= bb; ++g) gstart[g] = 0;
        } else {
            int pb = batch[i - 1];
            if (pb != bb) for (int g = pb + 1; g <= bb; ++g) gstart[g] = i;
        }
        if (i == NNODES - 1)
            for (int g = bb + 1; g <= NGRAPH; ++g) gstart[g] = NNODES;
    } else if (b < EB + SCAN_NB + XB) {
        int i = (b - EB - SCAN_NB) * 256 + t;
        if (i >= NNODES * FIN / 4) return;
        float4 v = x4[i];
        ushort4 o;
        o.x = f2bf(v.x); o.y = f2bf(v.y); o.z = f2bf(v.z); o.w = f2bf(v.w);
        xbf4[i] = o;
    } else if (b < EB + SCAN_NB + XB + W1B) {
        int id = (b - EB - SCAN_NB - XB) * 256 + t;
        int n = id & 255, k = id >> 8;                 // k in [0,128)
        W1t[n * FIN + (((k >> 3) ^ (n & 7)) << 3) + (k & 7)] = f2bf(W1[k * DTOT + n]);
    } else {
        int id = (b - EB - SCAN_NB - XB - W1B) * 256 + t;
        int n = id & 255, k = id >> 8;                 // k in [0,256)
        W2t[n * DTOT + (((k >> 3) ^ (n & 7)) << 3) + (k & 7)] = f2bf(W2[k * DTOT + n]);
    }
}

// ---------------- hierarchical scan (3 phases) ----------------
__global__ __launch_bounds__(256) void k_scan_blk(const int* __restrict__ deg,
                                                  int* __restrict__ rowptr,
                                                  int* __restrict__ bsum, int n) {
    __shared__ int wsum[4];
    int t = threadIdx.x;
    int i = blockIdx.x * 256 + t;
    int lane = t & 63, w = t >> 6;
    int v = (i < n) ? deg[i] : 0;
    int s = v;
#pragma unroll
    for (int off = 1; off < 64; off <<= 1) {
        int u = __shfl_up(s, off);
        if (lane >= off) s += u;
    }
    if (lane == 63) wsum[w] = s;
    __syncthreads();
    int add = 0;
#pragma unroll
    for (int j = 0; j < 3; ++j) add += (j < w) ? wsum[j] : 0;
    int incl = s + add;
    if (i < n) rowptr[i] = incl - v;
    if (t == 255) bsum[blockIdx.x] = incl;
}

__global__ __launch_bounds__(256) void k_scan_top(const int* __restrict__ bsum,
                                                  int* __restrict__ boff, int nb) {
    __shared__ int wsum[4];
    int t = threadIdx.x, lane = t & 63, w = t >> 6;
    int v = (t < nb) ? bsum[t] : 0;
    int s = v;
#pragma unroll
    for (int off = 1; off < 64; off <<= 1) {
        int u = __shfl_up(s, off);
        if (lane >= off) s += u;
    }
    if (lane == 63) wsum[w] = s;
    __syncthreads();
    int add = 0;
#pragma unroll
    for (int j = 0; j < 3; ++j) add += (j < w) ? wsum[j] : 0;
    boff[t] = s + add - v;
}

__global__ __launch_bounds__(256) void k_scan_add(int* __restrict__ rowptr,
                                                  const int* __restrict__ boff,
                                                  int n, int total) {
    int i = blockIdx.x * 256 + threadIdx.x;
    if (i < n) rowptr[i] += boff[i >> 8];
    else if (i == n) rowptr[n] = total;
}

__global__ void k_fill(const int* __restrict__ src, const int* __restrict__ dst,
                       const int* __restrict__ rowptr, int* __restrict__ cursor,
                       int* __restrict__ esrc, int E) {
    int e = blockIdx.x * blockDim.x + threadIdx.x;
    if (e >= E) return;
    int d = dst[e];
    int pos = rowptr[d] + atomicAdd(&cursor[d], 1);
    esrc[pos] = src[e];
}

// ---------------- MFMA GEMM: Cbf[M,256] = Abf[M,K] @ W[K,256], tile 128x128 (2 heads) ----------------
// Bt is pre-transposed/swizzled bf16 [256][K]; staging = contiguous uint4 copy.
template <int K>
__global__ __launch_bounds__(256) void k_gemm_mfma(const ushort* __restrict__ Abf,
                                                   const ushort* __restrict__ Bt,
                                                   ushort* __restrict__ Cbf,
                                                   float* __restrict__ ls,
                                                   float* __restrict__ ld_,
                                                   const float* __restrict__ a_src,
                                                   const float* __restrict__ a_dst,
                                                   int M) {
    __shared__ ushort Bl[128 * K];                 // K=128: 32 KB, K=256: 64 KB
    const int tid  = threadIdx.x;
    const int w    = tid >> 6;
    const int lane = tid & 63;
    const int l15  = lane & 15;
    const int quad = lane >> 4;
    const int m0 = blockIdx.y * 128;
    const int n0 = blockIdx.x * 128;
    const int hb = blockIdx.x * 2;                 // first head of this tile

    {   // stage B rows [n0, n0+128): straight contiguous copy (swizzle pre-baked)
        const uint4* sp = (const uint4*)(Bt + (size_t)n0 * K);
        uint4* dp = (uint4*)Bl;
#pragma unroll
        for (int idx = tid; idx < 128 * K / 8; idx += 256) dp[idx] = sp[idx];
    }
    __syncthreads();

    f32x4 acc[2][8];
#pragma unroll
    for (int mf = 0; mf < 2; ++mf)
#pragma unroll
        for (int nf = 0; nf < 8; ++nf)
            acc[mf][nf] = (f32x4){0.f, 0.f, 0.f, 0.f};

    const int rbase = m0 + w * 32;
    int rowA0 = rbase + l15;       if (rowA0 >= M) rowA0 = M - 1;
    int rowA1 = rbase + 16 + l15;  if (rowA1 >= M) rowA1 = M - 1;
    const ushort* pa0 = Abf + (size_t)rowA0 * K + quad * 8;
    const ushort* pa1 = Abf + (size_t)rowA1 * K + quad * 8;

#pragma unroll
    for (int ks = 0; ks < K / 32; ++ks) {
        bf16x8 a0 = *(const bf16x8*)(pa0 + ks * 32);
        bf16x8 a1 = *(const bf16x8*)(pa1 + ks * 32);
        bf16x8 bfr[8];
#pragma unroll
        for (int nf = 0; nf < 8; ++nf) {
            int n = nf * 16 + l15;
            int c = (ks * 4 + quad) ^ (n & 7);
            bfr[nf] = *(const bf16x8*)&Bl[n * K + (c << 3)];
        }
#pragma unroll
        for (int nf = 0; nf < 8; ++nf) {
            acc[0][nf] = __builtin_amdgcn_mfma_f32_16x16x32_bf16(a0, bfr[nf], acc[0][nf], 0, 0, 0);
            acc[1][nf] = __builtin_amdgcn_mfma_f32_16x16x32_bf16(a1, bfr[nf], acc[1][nf], 0, 0, 0);
        }
    }

    // epilogue: bf16 store + fused fp32 logits for heads hb, hb+1
    float as[8], ad[8];
#pragma unroll
    for (int nf = 0; nf < 8; ++nf) {
        int head = hb + (nf >> 2);
        as[nf] = a_src[head * HID + (nf & 3) * 16 + l15];
        ad[nf] = a_dst[head * HID + (nf & 3) * 16 + l15];
    }
#pragma unroll
    for (int mf = 0; mf < 2; ++mf) {
#pragma unroll
        for (int reg = 0; reg < 4; ++reg) {
            int row = rbase + mf * 16 + quad * 4 + reg;
            bool ok = row < M;
            if (ok) {
#pragma unroll
                for (int nf = 0; nf < 8; ++nf)
                    Cbf[(size_t)row * DTOT + n0 + nf * 16 + l15] = f2bf(acc[mf][nf][reg]);
            }
            float s0 = 0.f, d0 = 0.f, s1 = 0.f, d1 = 0.f;
#pragma unroll
            for (int nf = 0; nf < 4; ++nf) {
                s0 += acc[mf][nf][reg] * as[nf];
                d0 += acc[mf][nf][reg] * ad[nf];
                s1 += acc[mf][nf + 4][reg] * as[nf + 4];
                d1 += acc[mf][nf + 4][reg] * ad[nf + 4];
            }
#pragma unroll
            for (int off = 1; off < 16; off <<= 1) {
                s0 += __shfl_xor(s0, off);
                d0 += __shfl_xor(d0, off);
                s1 += __shfl_xor(s1, off);
                d1 += __shfl_xor(d1, off);
            }
            if (ok && l15 == 0) {
                ls[row * HEADS + hb]      = s0;
                ld_[row * HEADS + hb]     = d0;
                ls[row * HEADS + hb + 1]  = s1;
                ld_[row * HEADS + hb + 1] = d1;
            }
        }
    }
}

// ---------------- fused softmax + gather-aggregate + ELU (v2: edge-pair wave halves) ----------------
// One wave per node. half = lane>>5 picks edge of pair; l32 = lane&31 covers 8 channels
// (uint4 = 16B row load); head h = l32>>3. Halves merged via shfl_xor(32) at the end.
template <bool BF16OUT>
__global__ __launch_bounds__(256) void k_gat_aggr(const int* __restrict__ rowptr,
                                                  const int* __restrict__ esrc,
                                                  const ushort* __restrict__ Whbf,
                                                  const float* __restrict__ ls,
                                                  const float* __restrict__ ld_,
                                                  void* __restrict__ out) {
    const int wv   = threadIdx.x >> 6;
    const int lane = threadIdx.x & 63;
    const int i    = blockIdx.x * 4 + wv;
    if (i >= NNODES) return;
    const int half = lane >> 5;
    const int l32  = lane & 31;
    const int h    = l32 >> 3;
    const int e0 = rowptr[i], e1 = rowptr[i + 1];
    const float ldv = ld_[i * HEADS + h];

    // pass A: M = lrelu(max_s ls[s,h] + ldv)   (lrelu monotone)
    float mx = -INFINITY;
    for (int e = e0 + (l32 & 7) + 8 * half; e < e1; e += 16)
        mx = fmaxf(mx, ls[esrc[e] * HEADS + h]);
    mx = fmaxf(mx, __shfl_xor(mx, 1));
    mx = fmaxf(mx, __shfl_xor(mx, 2));
    mx = fmaxf(mx, __shfl_xor(mx, 4));
    mx = fmaxf(mx, __shfl_xor(mx, 32));
    float lvm = mx + ldv;
    const float M = lvm > 0.f ? lvm : ALPHA * lvm;

    // pass B: each half takes one edge of the pair
    float ac[8] = {};
    float z = 0.f;
    const int ch = 8 * l32;
    int e = e0 + half;
    for (; e + 2 < e1; e += 4) {
        int s0 = esrc[e], s1 = esrc[e + 2];
        float l0 = ls[s0 * HEADS + h] + ldv;
        float l1 = ls[s1 * HEADS + h] + ldv;
        uint4 u0 = *(const uint4*)&Whbf[(size_t)s0 * DTOT + ch];
        uint4 u1 = *(const uint4*)&Whbf[(size_t)s1 * DTOT + ch];
        float p0 = __expf((l0 > 0.f ? l0 : ALPHA * l0) - M);
        float p1 = __expf((l1 > 0.f ? l1 : ALPHA * l1) - M);
        z += p0 + p1;
        ac[0] = fmaf(p0, blo(u0.x), ac[0]); ac[1] = fmaf(p0, bhi(u0.x), ac[1]);
        ac[2] = fmaf(p0, blo(u0.y), ac[2]); ac[3] = fmaf(p0, bhi(u0.y), ac[3]);
        ac[4] = fmaf(p0, blo(u0.z), ac[4]); ac[5] = fmaf(p0, bhi(u0.z), ac[5]);
        ac[6] = fmaf(p0, blo(u0.w), ac[6]); ac[7] = fmaf(p0, bhi(u0.w), ac[7]);
        ac[0] = fmaf(p1, blo(u1.x), ac[0]); ac[1] = fmaf(p1, bhi(u1.x), ac[1]);
        ac[2] = fmaf(p1, blo(u1.y), ac[2]); ac[3] = fmaf(p1, bhi(u1.y), ac[3]);
        ac[4] = fmaf(p1, blo(u1.z), ac[4]); ac[5] = fmaf(p1, bhi(u1.z), ac[5]);
        ac[6] = fmaf(p1, blo(u1.w), ac[6]); ac[7] = fmaf(p1, bhi(u1.w), ac[7]);
    }
    for (; e < e1; e += 2) {
        int s0 = esrc[e];
        float l0 = ls[s0 * HEADS + h] + ldv;
        uint4 u0 = *(const uint4*)&Whbf[(size_t)s0 * DTOT + ch];
        float p0 = __expf((l0 > 0.f ? l0 : ALPHA * l0) - M);
        z += p0;
        ac[0] = fmaf(p0, blo(u0.x), ac[0]); ac[1] = fmaf(p0, bhi(u0.x), ac[1]);
        ac[2] = fmaf(p0, blo(u0.y), ac[2]); ac[3] = fmaf(p0, bhi(u0.y), ac[3]);
        ac[4] = fmaf(p0, blo(u0.z), ac[4]); ac[5] = fmaf(p0, bhi(u0.z), ac[5]);
        ac[6] = fmaf(p0, blo(u0.w), ac[6]); ac[7] = fmaf(p0, bhi(u0.w), ac[7]);
    }

    // merge halves
#pragma unroll
    for (int j = 0; j < 8; ++j) ac[j] += __shfl_xor(ac[j], 32);
    z += __shfl_xor(z, 32);

    if (half == 0) {
        const float inv = 1.f / (z + 1e-16f);
        float v[8];
#pragma unroll
        for (int j = 0; j < 8; ++j) {
            float t = ac[j] * inv;
            v[j] = t > 0.f ? t : __expf(t) - 1.f;
        }
        if (BF16OUT) {
            ushort4 pk;
            pk.x = f2bf(v[0]); pk.y = f2bf(v[1]); pk.z = f2bf(v[2]); pk.w = f2bf(v[3]);
            ushort4 pk2;
            pk2.x = f2bf(v[4]); pk2.y = f2bf(v[5]); pk2.z = f2bf(v[6]); pk2.w = f2bf(v[7]);
            *(ushort4*)((ushort*)out + (size_t)i * DTOT + ch)     = pk;
            *(ushort4*)((ushort*)out + (size_t)i * DTOT + ch + 4) = pk2;
        } else {
            *(float4*)((float*)out + (size_t)i * DTOT + ch)     = make_float4(v[0], v[1], v[2], v[3]);
            *(float4*)((float*)out + (size_t)i * DTOT + ch + 4) = make_float4(v[4], v[5], v[6], v[7]);
        }
    }
}

// ---------------- pooling (max + mean per graph) ----------------
__global__ __launch_bounds__(256) void k_pool(const float* __restrict__ h2,
                                              const int* __restrict__ gstart,
                                              float* __restrict__ pooled) {
    int g = blockIdx.x, f = threadIdx.x;
    int s = gstart[g], e = gstart[g + 1];
    float mx = -INFINITY, sm = 0.f;
    for (int n = s; n < e; ++n) {
        float v = h2[(size_t)n * DTOT + f];
        mx = fmaxf(mx, v);
        sm += v;
    }
    int cnt = e - s;
    if (cnt <= 0) mx = 0.f;
    pooled[g * 2 * DTOT + f]        = mx;
    pooled[g * 2 * DTOT + DTOT + f] = sm / (float)(cnt > 0 ? cnt : 1);
}

// ---------------- final linear (fp32 output) ----------------
__global__ __launch_bounds__(64) void k_final(const float* __restrict__ pooled,
                                              const float* __restrict__ W,
                                              const float* __restrict__ b,
                                              float* __restrict__ out) {
    int g = blockIdx.x, lane = threadIdx.x;
    for (int c = 0; c < NCLS; ++c) {
        float acc = 0.f;
        for (int k = lane; k < 2 * DTOT; k += 64)
            acc += pooled[g * 2 * DTOT + k] * W[k * NCLS + c];
#pragma unroll
        for (int off = 32; off; off >>= 1) acc += __shfl_down(acc, off);
        if (lane == 0)
            out[g * NCLS + c] = acc + b[c];
    }
}

extern "C" void kernel_launch(void* const* d_in, const int* in_sizes, int n_in,
                              void* d_out, int out_size, void* d_ws, size_t ws_size,
                              hipStream_t stream) {
    const float* x     = (const float*)d_in[0];
    const int*   ei    = (const int*)d_in[1];
    const int*   batch = (const int*)d_in[2];
    const float* W1    = (const float*)d_in[3];
    const float* a1s   = (const float*)d_in[4];
    const float* a1d   = (const float*)d_in[5];
    const float* W2    = (const float*)d_in[6];
    const float* a2s   = (const float*)d_in[7];
    const float* a2d   = (const float*)d_in[8];
    const float* linW  = (const float*)d_in[9];
    const float* linb  = (const float*)d_in[10];
    float* out = (float*)d_out;

    const int* src = ei;
    const int* dst = ei + NEDGES;

    size_t off = 0;
    char* base = (char*)d_ws;
    auto alloc = [&](size_t bytes) -> void* {
        void* p = base + off;
        off += (bytes + 255) & ~(size_t)255;
        return p;
    };
    ushort* xbf    = (ushort*)alloc((size_t)NNODES * FIN * 2);
    ushort* Whbf   = (ushort*)alloc((size_t)NNODES * DTOT * 2);
    ushort* h1bf   = (ushort*)alloc((size_t)NNODES * DTOT * 2);
    float*  h2     = (float*)alloc((size_t)NNODES * DTOT * 4);
    float*  ls     = (float*)alloc((size_t)NNODES * HEADS * 4);
    float*  ld_    = (float*)alloc((size_t)NNODES * HEADS * 4);
    int*    deg    = (int*)alloc((size_t)NNODES * 4);
    int*    rowptr = (int*)alloc((size_t)(NNODES + 1) * 4);
    int*    cursor = (int*)alloc((size_t)NNODES * 4);
    int*    esrc   = (int*)alloc((size_t)NEDGES * 4);
    int*    gstart = (int*)alloc((size_t)(NGRAPH + 1) * 4);
    float*  pooled = (float*)alloc((size_t)NGRAPH * 2 * DTOT * 4);
    int*    bsum   = (int*)alloc((size_t)SCAN_NB * 4);
    int*    boff   = (int*)alloc((size_t)256 * 4);
    ushort* W1t    = (ushort*)alloc((size_t)DTOT * FIN * 2);   // [256][128] swizzled bf16
    ushort* W2t    = (ushort*)alloc((size_t)DTOT * DTOT * 2);  // [256][256] swizzled bf16

    hipMemsetAsync(deg, 0, (size_t)NNODES * 4, stream);
    hipMemsetAsync(cursor, 0, (size_t)NNODES * 4, stream);

    int setup_blocks = EB + SCAN_NB + XB + W1B + W2B;
    k_setup<<<setup_blocks, 256, 0, stream>>>(dst, deg, batch, gstart,
                                              (const float4*)x, (ushort4*)xbf,
                                              W1, W1t, W2, W2t);
    k_scan_blk<<<SCAN_NB, 256, 0, stream>>>(deg, rowptr, bsum, NNODES);
    k_scan_top<<<1, 256, 0, stream>>>(bsum, boff, SCAN_NB);
    k_scan_add<<<(NNODES + 256) / 256, 256, 0, stream>>>(rowptr, boff, NNODES, NEDGES);
    k_fill<<<EB, 256, 0, stream>>>(src, dst, rowptr, cursor, esrc, NEDGES);

    dim3 ggrid(2, (NNODES + 127) / 128);   // n-tile = 128 cols (2 heads)

    // Layer 1
    k_gemm_mfma<FIN><<<ggrid, 256, 0, stream>>>(xbf, W1t, Whbf, ls, ld_, a1s, a1d, NNODES);
    k_gat_aggr<true><<<(NNODES + 3) / 4, 256, 0, stream>>>(rowptr, esrc, Whbf, ls, ld_, h1bf);

    // Layer 2
    k_gemm_mfma<DTOT><<<ggrid, 256, 0, stream>>>(h1bf, W2t, Whbf, ls, ld_, a2s, a2d, NNODES);
    k_gat_aggr<false><<<(NNODES + 3) / 4, 256, 0, stream>>>(rowptr, esrc, Whbf, ls, ld_, h2);

    // Pool + head
    k_pool<<<NGRAPH, 256, 0, stream>>>(h2, gstart, pooled);
    k_final<<<NGRAPH, 64, 0, stream>>>(pooled, linW, linb, out);
}